// Round 5
// baseline (296.482 us; speedup 1.0000x reference)
//
#include <hip/hip_runtime.h>
#include <math.h>

// Problem constants
#define BATCH   8
#define SEQLEN  2048
#define DMODEL  1024
#define KFREQ   513        // unique half-spectrum freqs 0..512
#define KF      528        // padded freq count; 2*KF = 1056
#define K2      (2*KF)     // 1056: [0,KF)=real, [KF,2KF)=imag
#define NPAD1   1152       // K2 padded to multiple of 128 (B-operand rows)
#define KPAD    1088       // K2 padded to multiple of 64 (GEMM-Y K-dim / row stride)
#define BT_ROWS (BATCH*SEQLEN)   // 16384
#define NC      32         // time chunks for parallel scan
#define TC      64         // chunk length; NC*TC == SEQLEN

static_assert(NC * TC == SEQLEN, "chunking must cover SEQLEN");

typedef __attribute__((ext_vector_type(4))) float f32x4;
typedef __attribute__((ext_vector_type(8))) short bf16x8;   // 8 bf16 in 4 VGPRs
typedef unsigned short ushort_t;

__device__ __forceinline__ ushort_t f2bf(float f) {
    union { float f; unsigned u; } v; v.f = f;
    unsigned r = v.u + 0x7FFFu + ((v.u >> 16) & 1u);   // RNE
    return (ushort_t)(r >> 16);
}
__device__ __forceinline__ float bf2f(ushort_t b) {
    union { unsigned u; float f; } v; v.u = ((unsigned)b) << 16;
    return v.f;
}

__device__ __forceinline__ void async_cp16(const void* g, void* l) {
    __builtin_amdgcn_global_load_lds(
        (const __attribute__((address_space(1))) void*)g,
        (__attribute__((address_space(3))) void*)l, 16, 0, 0);
}

// ---------------------------------------------------------------------------
// lambda_k = (1 - i w)/(1 + i w),  w = Im(FFT(a_full))[k]
// ---------------------------------------------------------------------------
__global__ __launch_bounds__(1024) void compute_lambda(const float* __restrict__ p,
                                                        float* __restrict__ lam) {
    __shared__ float stab[1024];
    const int tid = threadIdx.x;
    stab[tid] = sinf((float)tid * (6.28318530717958647692f / 1024.0f));
    __syncthreads();
    if (tid < KF) {
        if (tid < KFREQ) {
            float om = 0.0f;
            for (int j = 1; j <= 511; ++j)
                om = fmaf(p[j - 1], stab[(j * tid) & 1023], om);
            om *= -2.0f;
            const float w2 = om * om;
            const float den = 1.0f + w2;
            lam[tid]      = (1.0f - w2) / den;
            lam[KF + tid] = -2.0f * om / den;
        } else {
            lam[tid] = 0.0f;
            lam[KF + tid] = 0.0f;
        }
    }
}

// ---------------------------------------------------------------------------
// Trig matrix directly in bf16, [NPAD1][1024]:
//   rows [0,513):      cos(2pi kf n/1024) * scale
//   rows [KF,KF+513):  -sin(2pi kf n/1024) * scale
//   other rows 0 (pad).
// mode 0: scale=1;  mode 1: scale = w/1024, w = (kf==0||kf==512)?1:2.
// ---------------------------------------------------------------------------
__global__ __launch_bounds__(256) void gen_Tb(ushort_t* __restrict__ T, int mode) {
    __shared__ float stab[1024];
    for (int j = threadIdx.x; j < 1024; j += 256)
        stab[j] = sinf((float)j * (6.28318530717958647692f / 1024.0f));
    __syncthreads();

    const int i = blockIdx.x * 256 + threadIdx.x;   // 8 elements per thread
    if (i >= NPAD1 * DMODEL / 8) return;
    const int row = i >> 7;
    const int nb  = (i & 127) << 3;

    ushort_t o[8] = {0, 0, 0, 0, 0, 0, 0, 0};
    const bool re = (row < KFREQ);
    const bool im = (row >= KF && row < KF + KFREQ);
    if (re || im) {
        const int kf = re ? row : row - KF;
        float scale = 1.0f;
        if (mode == 1) scale = ((kf == 0 || kf == 512) ? 1.0f : 2.0f) / 1024.0f;
        int m = (kf * nb) & 1023;
#pragma unroll
        for (int j = 0; j < 8; ++j) {
            const float v = im ? -stab[m] : stab[(m + 256) & 1023];
            o[j] = f2bf(v * scale);
            m = (m + kf) & 1023;
        }
    }
    reinterpret_cast<bf16x8*>(T)[i] = *reinterpret_cast<bf16x8*>(o);
}

// ---------------------------------------------------------------------------
// Transpose-convert: dst[c][r] (bf16, 1024x1024) = src[r][c] (fp32)
// ---------------------------------------------------------------------------
__global__ __launch_bounds__(256) void transp_conv(const float* __restrict__ s,
                                                   ushort_t* __restrict__ d) {
    __shared__ float tile[64][65];
    const int bx = blockIdx.x * 64;
    const int by = blockIdx.y * 64;
    const int lx = threadIdx.x & 63;
    const int ly = threadIdx.x >> 6;
#pragma unroll
    for (int i = 0; i < 16; ++i) {
        const int r = ly + i * 4;
        tile[r][lx] = s[(size_t)(by + r) * DMODEL + bx + lx];
    }
    __syncthreads();
#pragma unroll
    for (int i = 0; i < 16; ++i) {
        const int r = ly + i * 4;
        d[(size_t)(bx + r) * DMODEL + by + lx] = f2bf(tile[lx][r]);
    }
}

// ---------------------------------------------------------------------------
// bf16 MFMA GEMM: C[M][ldc] = A[M][K](bf16) @ B[Nrows][K]^T
// 128x128 tile, BK=64, 4 waves, 16x16x32 MFMA, global_load_lds width-16.
// Epilogue columns: col < Nact -> value; Nact <= col < Nstore -> 0; else skip.
// EPI:   C += Dv[n]*uu[m*DMODEL+n]  (fp32 out only, Nact==Nstore==1024)
// OUTBF: store bf16 instead of fp32
// M must be a multiple of 128; K a multiple of 64; B has >= n0+128 rows.
// ---------------------------------------------------------------------------
template <bool EPI, bool OUTBF>
__global__ __launch_bounds__(256) void gemm_bf16(const ushort_t* __restrict__ A,
                                                 const ushort_t* __restrict__ B,
                                                 void* __restrict__ Cv,
                                                 int M, int Nact, int Nstore,
                                                 int K, int ldc,
                                                 const float* __restrict__ uu,
                                                 const float* __restrict__ Dv) {
    __shared__ ushort_t As[128 * 64];   // 16 KB
    __shared__ ushort_t Bs[128 * 64];   // 16 KB
    const int tid  = threadIdx.x;
    const int lane = tid & 63;
    const int w    = tid >> 6;
    const int m0 = blockIdx.x * 128;
    const int n0 = blockIdx.y * 128;
    const int wr = (w >> 1) * 64;
    const int wc = (w & 1) * 64;

    f32x4 acc[4][4] = {};

    // staging: issue q covers rows q*32..q*32+31 of the 128x64 tile
    const int srow = tid >> 3;          // 0..31
    const int scol = (tid & 7) * 8;     // 0..56
    const int lr = lane & 15;
    const int lk = (lane >> 4) * 8;

    for (int k0 = 0; k0 < K; k0 += 64) {
        __syncthreads();
#pragma unroll
        for (int q = 0; q < 4; ++q) {
            async_cp16(A + (size_t)(m0 + q * 32 + srow) * K + k0 + scol,
                       As + q * 2048 + (w << 9));
            async_cp16(B + (size_t)(n0 + q * 32 + srow) * K + k0 + scol,
                       Bs + q * 2048 + (w << 9));
        }
        __syncthreads();

        bf16x8 fa[4][2], fb[4][2];
#pragma unroll
        for (int mi = 0; mi < 4; ++mi)
#pragma unroll
            for (int kk = 0; kk < 2; ++kk)
                fa[mi][kk] = *reinterpret_cast<const bf16x8*>(
                    &As[(wr + mi * 16 + lr) * 64 + kk * 32 + lk]);
#pragma unroll
        for (int ni = 0; ni < 4; ++ni)
#pragma unroll
            for (int kk = 0; kk < 2; ++kk)
                fb[ni][kk] = *reinterpret_cast<const bf16x8*>(
                    &Bs[(wc + ni * 16 + lr) * 64 + kk * 32 + lk]);
#pragma unroll
        for (int mi = 0; mi < 4; ++mi)
#pragma unroll
            for (int ni = 0; ni < 4; ++ni) {
                acc[mi][ni] = __builtin_amdgcn_mfma_f32_16x16x32_bf16(
                    fa[mi][0], fb[ni][0], acc[mi][ni], 0, 0, 0);
                acc[mi][ni] = __builtin_amdgcn_mfma_f32_16x16x32_bf16(
                    fa[mi][1], fb[ni][1], acc[mi][ni], 0, 0, 0);
            }
    }

    const int rbase = (lane >> 4) * 4;
#pragma unroll
    for (int mi = 0; mi < 4; ++mi) {
#pragma unroll
        for (int ni = 0; ni < 4; ++ni) {
            const int col = n0 + wc + ni * 16 + lr;
            if (col >= Nstore) continue;
            const bool act = (col < Nact);
#pragma unroll
            for (int j = 0; j < 4; ++j) {
                const int row = m0 + wr + mi * 16 + rbase + j;
                float v = act ? acc[mi][ni][j] : 0.0f;
                if (EPI && act) v = fmaf(Dv[col], uu[(size_t)row * DMODEL + col], v);
                if (OUTBF)
                    ((ushort_t*)Cv)[(size_t)row * ldc + col] = f2bf(v);
                else
                    ((float*)Cv)[(size_t)row * ldc + col] = v;
            }
        }
    }
}

// ---------------------------------------------------------------------------
// fp32 -> bf16 (flat, 8 elements/thread)
// ---------------------------------------------------------------------------
__global__ __launch_bounds__(256) void conv_bf16(const float* __restrict__ s,
                                                 ushort_t* __restrict__ d, int n8) {
    const int i = blockIdx.x * 256 + threadIdx.x;
    if (i >= n8) return;
    const float4 a = reinterpret_cast<const float4*>(s)[2 * i];
    const float4 b = reinterpret_cast<const float4*>(s)[2 * i + 1];
    ushort_t o[8] = {f2bf(a.x), f2bf(a.y), f2bf(a.z), f2bf(a.w),
                     f2bf(b.x), f2bf(b.y), f2bf(b.z), f2bf(b.w)};
    reinterpret_cast<bf16x8*>(d)[i] = *reinterpret_cast<bf16x8*>(o);
}

// ---------------------------------------------------------------------------
// Chunked parallel scan, in place on bf16 UHb [bt][KPAD]
// (fp32 accumulate in registers; bf16 rounding only at stores)
// ---------------------------------------------------------------------------
__global__ __launch_bounds__(256) void scan_local(ushort_t* __restrict__ UHb,
                                                  const float* __restrict__ lam) {
    const int gid = blockIdx.x * 256 + threadIdx.x;
    if (gid >= BATCH * NC * KF) return;
    const int kf = gid % KF;
    const int bc = gid / KF;
    const int c = bc % NC;
    const int b = bc / NC;
    const float lr = lam[kf], li = lam[KF + kf];
    ushort_t* base = UHb + ((size_t)(b * SEQLEN + c * TC)) * KPAD + kf;
    float hr = 0.0f, hi = 0.0f;
    for (int t = 0; t < TC; ++t) {
        const float ur = bf2f(base[(size_t)t * KPAD]);
        const float ui = bf2f(base[(size_t)t * KPAD + KF]);
        const float nr = fmaf(lr, hr, fmaf(-li, hi, ur));
        const float ni = fmaf(lr, hi, fmaf(li, hr, ui));
        base[(size_t)t * KPAD]      = f2bf(nr);
        base[(size_t)t * KPAD + KF] = f2bf(ni);
        hr = nr; hi = ni;
    }
}

__global__ __launch_bounds__(256) void scan_carry(const ushort_t* __restrict__ UHb,
                                                  const float* __restrict__ lam,
                                                  float* __restrict__ Ac) {
    const int gid = blockIdx.x * 256 + threadIdx.x;
    if (gid >= BATCH * KF) return;
    const int kf = gid % KF;
    const int b = gid / KF;
    const float lr = lam[kf], li = lam[KF + kf];
    float pr = lr, pi = li;          // lambda^64 via 6 squarings
    for (int s = 0; s < 6; ++s) {
        const float nr = pr * pr - pi * pi;
        const float ni = 2.0f * pr * pi;
        pr = nr; pi = ni;
    }
    float er = 0.0f, ei = 0.0f;
    for (int c = 0; c < NC; ++c) {
        const size_t ai = (size_t)(b * NC + c) * KF + kf;
        Ac[ai] = er;
        Ac[(size_t)BATCH * NC * KF + ai] = ei;
        const size_t gi = ((size_t)(b * SEQLEN + c * TC + TC - 1)) * KPAD + kf;
        const float gr = bf2f(UHb[gi]);
        const float gm = bf2f(UHb[gi + KF]);
        const float nr = fmaf(pr, er, fmaf(-pi, ei, gr));
        const float ni = fmaf(pr, ei, fmaf(pi, er, gm));
        er = nr; ei = ni;
    }
}

// H_global[tau] = H_local[tau] + lambda^{tau+1} * carry   (in place, bf16)
__global__ __launch_bounds__(256) void scan_apply(ushort_t* __restrict__ UHb,
                                                  const float* __restrict__ lam,
                                                  const float* __restrict__ Ac) {
    const int gid = blockIdx.x * 256 + threadIdx.x;
    if (gid >= BATCH * NC * KF) return;
    const int kf = gid % KF;
    const int bc = gid / KF;
    const int c = bc % NC;
    const int b = bc / NC;
    if (c == 0) return;                        // carry is zero
    const float er = Ac[gid];
    const float ei = Ac[(size_t)BATCH * NC * KF + gid];
    const float lr = lam[kf], li = lam[KF + kf];
    ushort_t* base = UHb + ((size_t)(b * SEQLEN + c * TC)) * KPAD + kf;
    float pr = lr, pi = li;   // lambda^1
    for (int t = 0; t < TC; ++t) {
        const float hr = bf2f(base[(size_t)t * KPAD]);
        const float hi = bf2f(base[(size_t)t * KPAD + KF]);
        base[(size_t)t * KPAD]      = f2bf(fmaf(pr, er, fmaf(-pi, ei, hr)));
        base[(size_t)t * KPAD + KF] = f2bf(fmaf(pr, ei, fmaf(pi, er, hi)));
        const float nr = fmaf(pr, lr, -pi * li);
        const float ni = fmaf(pr, li, pi * lr);
        pr = nr; pi = ni;
    }
}

// ---------------------------------------------------------------------------
extern "C" void kernel_launch(void* const* d_in, const int* in_sizes, int n_in,
                              void* d_out, int out_size, void* d_ws, size_t ws_size,
                              hipStream_t stream) {
    const float* u  = (const float*)d_in[0];  // [B][S][D]
    const float* ap = (const float*)d_in[1];  // [512]
    const float* Bw = (const float*)d_in[2];  // [N][D]
    const float* Cw = (const float*)d_in[3];  // [D][N]
    const float* Dv = (const float*)d_in[4];  // [D]
    float* out = (float*)d_out;               // [B][S][D]

    char* ws = (char*)d_ws;
    size_t off = 0;
    auto carve = [&](size_t bytes) { char* p = ws + off; off += (bytes + 255) & ~(size_t)255; return p; };

    ushort_t* UHb  = (ushort_t*)carve((size_t)BT_ROWS * KPAD * sizeof(ushort_t));   // 35.7 MB
    ushort_t* ub   = (ushort_t*)carve((size_t)BT_ROWS * DMODEL * sizeof(ushort_t)); // 33.6 MB
    ushort_t* T1b  = (ushort_t*)carve((size_t)NPAD1 * DMODEL * sizeof(ushort_t));
    ushort_t* T2b  = (ushort_t*)carve((size_t)NPAD1 * DMODEL * sizeof(ushort_t));
    ushort_t* BwTb = (ushort_t*)carve((size_t)DMODEL * DMODEL * sizeof(ushort_t));
    ushort_t* Cwb  = (ushort_t*)carve((size_t)DMODEL * DMODEL * sizeof(ushort_t));
    ushort_t* W1b  = (ushort_t*)carve((size_t)NPAD1 * DMODEL * sizeof(ushort_t));
    ushort_t* W2b  = (ushort_t*)carve((size_t)DMODEL * KPAD * sizeof(ushort_t));
    float*    lam  = (float*)   carve(2 * KF * sizeof(float));
    float*    Ac   = (float*)   carve((size_t)2 * BATCH * NC * KF * sizeof(float));

    // 1) eigenvalues
    compute_lambda<<<1, 1024, 0, stream>>>(ap, lam);

    // 2) trig matrices (bf16) + operand conversions
    gen_Tb<<<NPAD1 * DMODEL / 8 / 256, 256, 0, stream>>>(T1b, 0);
    gen_Tb<<<NPAD1 * DMODEL / 8 / 256, 256, 0, stream>>>(T2b, 1);
    {
        dim3 g(DMODEL / 64, DMODEL / 64);
        transp_conv<<<g, 256, 0, stream>>>(Bw, BwTb);
    }
    conv_bf16<<<DMODEL * DMODEL / 8 / 256, 256, 0, stream>>>(Cw, Cwb, DMODEL * DMODEL / 8);

    // 3) W1b[k2][d] = T1b @ BwTb^T   (bf16 out; pad rows of T1b are 0)
    {
        dim3 g(NPAD1 / 128, DMODEL / 128);
        gemm_bf16<false, true><<<g, 256, 0, stream>>>(T1b, BwTb, W1b,
            NPAD1, DMODEL, DMODEL, DMODEL, DMODEL, nullptr, nullptr);
    }
    // 4) W2b[d][k2pad] = Cwb @ T2b^T   (bf16 out; cols 1056..1087 zeroed)
    {
        dim3 g(DMODEL / 128, NPAD1 / 128);
        gemm_bf16<false, true><<<g, 256, 0, stream>>>(Cwb, T2b, W2b,
            DMODEL, K2, KPAD, DMODEL, KPAD, nullptr, nullptr);
    }

    // 5) u -> bf16
    conv_bf16<<<BT_ROWS * (DMODEL / 8) / 256, 256, 0, stream>>>(u, ub, BT_ROWS * (DMODEL / 8));

    // 6) UHb[bt][k2pad] = ub @ W1b^T   (bf16 out; cols 1056..1087 zeroed)
    {
        dim3 g(BT_ROWS / 128, NPAD1 / 128);
        gemm_bf16<false, true><<<g, 256, 0, stream>>>(ub, W1b, UHb,
            BT_ROWS, K2, KPAD, DMODEL, KPAD, nullptr, nullptr);
    }

    // 7) scan over time (in place on bf16): local, carry, apply
    scan_local<<<(BATCH * NC * KF + 255) / 256, 256, 0, stream>>>(UHb, lam);
    scan_carry<<<(BATCH * KF + 255) / 256, 256, 0, stream>>>(UHb, lam, Ac);
    scan_apply<<<(BATCH * NC * KF + 255) / 256, 256, 0, stream>>>(UHb, lam, Ac);

    // 8) y = UHb @ W2b^T + D*u   (fp32 out; K = KPAD, pad cols are zero)
    {
        dim3 g(BT_ROWS / 128, DMODEL / 128);
        gemm_bf16<true, false><<<g, 256, 0, stream>>>(UHb, W2b, out,
            BT_ROWS, DMODEL, DMODEL, KPAD, DMODEL, u, Dv);
    }
}

// Round 6
// 243.286 us; speedup vs baseline: 1.2187x; 1.2187x over previous
//
#include <hip/hip_runtime.h>
#include <math.h>

// Problem constants
#define BATCH   8
#define SEQLEN  2048
#define DMODEL  1024
#define KFREQ   513        // unique half-spectrum freqs 0..512
#define NSPEC   1024       // exact: 513 Re (cols 0..512) + 511 Im (cols 513..1023, k=1..511)
#define BT_ROWS (BATCH*SEQLEN)   // 16384
#define NC      32         // time chunks for parallel scan
#define TC      64         // chunk length; NC*TC == SEQLEN

static_assert(NC * TC == SEQLEN, "chunking must cover SEQLEN");

typedef __attribute__((ext_vector_type(4))) float f32x4;
typedef __attribute__((ext_vector_type(8))) short bf16x8;   // 8 bf16 in 4 VGPRs
typedef unsigned short ushort_t;

__device__ __forceinline__ ushort_t f2bf(float f) {
    union { float f; unsigned u; } v; v.f = f;
    unsigned r = v.u + 0x7FFFu + ((v.u >> 16) & 1u);   // RNE
    return (ushort_t)(r >> 16);
}
__device__ __forceinline__ float bf2f(ushort_t b) {
    union { unsigned u; float f; } v; v.u = ((unsigned)b) << 16;
    return v.f;
}

__device__ __forceinline__ void async_cp16(const void* g, void* l) {
    __builtin_amdgcn_global_load_lds(
        (const __attribute__((address_space(1))) void*)g,
        (__attribute__((address_space(3))) void*)l, 16, 0, 0);
}

// ---------------------------------------------------------------------------
// lambda_k = (1 - i w)/(1 + i w),  w = Im(FFT(a_full))[k]
// layout: lam[k] = Re(lambda_k), k=0..512;  lam[512+k] = Im(lambda_k), k=1..511
// (Im is identically 0 at k=0 and k=512 since omega=0 there.)
// ---------------------------------------------------------------------------
__global__ __launch_bounds__(1024) void compute_lambda(const float* __restrict__ p,
                                                        float* __restrict__ lam) {
    __shared__ float stab[1024];
    const int tid = threadIdx.x;
    stab[tid] = sinf((float)tid * (6.28318530717958647692f / 1024.0f));
    __syncthreads();
    if (tid < KFREQ) {
        float om = 0.0f;
        for (int j = 1; j <= 511; ++j)
            om = fmaf(p[j - 1], stab[(j * tid) & 1023], om);
        om *= -2.0f;
        const float w2 = om * om;
        const float den = 1.0f + w2;
        lam[tid] = (1.0f - w2) / den;
        if (tid >= 1 && tid <= 511)
            lam[512 + tid] = -2.0f * om / den;
    }
}

// ---------------------------------------------------------------------------
// Trig matrix in bf16, [NSPEC][DMODEL]:
//   row r in [0,513):     cos(2pi r n/1024) * scale_re
//   row r in [513,1024):  k=r-512 in [1,511];  -sin(2pi k n/1024) * scale_im
// mode 0: scale=1.  mode 1: scale_re = ((r==0||r==512)?1:2)/1024; scale_im = 2/1024.
// ---------------------------------------------------------------------------
__global__ __launch_bounds__(256) void gen_Tb(ushort_t* __restrict__ T, int mode) {
    __shared__ float stab[1024];
    for (int j = threadIdx.x; j < 1024; j += 256)
        stab[j] = sinf((float)j * (6.28318530717958647692f / 1024.0f));
    __syncthreads();

    const int i = blockIdx.x * 256 + threadIdx.x;   // 8 elements per thread
    if (i >= NSPEC * DMODEL / 8) return;
    const int row = i >> 7;
    const int nb  = (i & 127) << 3;

    const bool re = (row < KFREQ);
    const int kf = re ? row : row - 512;            // im: 1..511
    float scale = 1.0f;
    if (mode == 1)
        scale = (re ? ((kf == 0 || kf == 512) ? 1.0f : 2.0f) : 2.0f) / 1024.0f;

    ushort_t o[8];
    int m = (kf * nb) & 1023;
#pragma unroll
    for (int j = 0; j < 8; ++j) {
        const float v = re ? stab[(m + 256) & 1023] : -stab[m];
        o[j] = f2bf(v * scale);
        m = (m + kf) & 1023;
    }
    reinterpret_cast<bf16x8*>(T)[i] = *reinterpret_cast<bf16x8*>(o);
}

// ---------------------------------------------------------------------------
// Transpose-convert: dst[c][r] (bf16, 1024x1024) = src[r][c] (fp32)
// ---------------------------------------------------------------------------
__global__ __launch_bounds__(256) void transp_conv(const float* __restrict__ s,
                                                   ushort_t* __restrict__ d) {
    __shared__ float tile[64][65];
    const int bx = blockIdx.x * 64;
    const int by = blockIdx.y * 64;
    const int lx = threadIdx.x & 63;
    const int ly = threadIdx.x >> 6;
#pragma unroll
    for (int i = 0; i < 16; ++i) {
        const int r = ly + i * 4;
        tile[r][lx] = s[(size_t)(by + r) * DMODEL + bx + lx];
    }
    __syncthreads();
#pragma unroll
    for (int i = 0; i < 16; ++i) {
        const int r = ly + i * 4;
        d[(size_t)(bx + r) * DMODEL + by + lx] = f2bf(tile[lx][r]);
    }
}

// ---------------------------------------------------------------------------
// 128x128 BK=32 bf16 MFMA GEMM (round-4-proven) — used for the two small
// weight-precompute GEMMs. C (bf16) [M][N] = A[M][K] @ B[N][K]^T.
// M,N multiples of 128; K multiple of 32.
// ---------------------------------------------------------------------------
__global__ __launch_bounds__(256) void gemm128(const ushort_t* __restrict__ A,
                                               const ushort_t* __restrict__ B,
                                               ushort_t* __restrict__ C,
                                               int M, int N, int K) {
    __shared__ ushort_t As[128 * 32];
    __shared__ ushort_t Bs[128 * 32];
    const int tid  = threadIdx.x;
    const int lane = tid & 63;
    const int w    = tid >> 6;
    const int m0 = blockIdx.x * 128;
    const int n0 = blockIdx.y * 128;
    const int wr = (w >> 1) * 64;
    const int wc = (w & 1) * 64;

    f32x4 acc[4][4] = {};

    const int pos  = w * 512 + lane * 8;
    const int srow = pos >> 5;
    const int scol = pos & 31;
    const int lr = lane & 15;
    const int lk = (lane >> 4) * 8;

    for (int k0 = 0; k0 < K; k0 += 32) {
        __syncthreads();
        async_cp16(A + (size_t)(m0 + srow)      * K + k0 + scol, As + w * 512);
        async_cp16(A + (size_t)(m0 + srow + 64) * K + k0 + scol, As + 2048 + w * 512);
        async_cp16(B + (size_t)(n0 + srow)      * K + k0 + scol, Bs + w * 512);
        async_cp16(B + (size_t)(n0 + srow + 64) * K + k0 + scol, Bs + 2048 + w * 512);
        __syncthreads();

        bf16x8 fa[4], fb[4];
#pragma unroll
        for (int mi = 0; mi < 4; ++mi)
            fa[mi] = *reinterpret_cast<const bf16x8*>(&As[(wr + mi * 16 + lr) * 32 + lk]);
#pragma unroll
        for (int ni = 0; ni < 4; ++ni)
            fb[ni] = *reinterpret_cast<const bf16x8*>(&Bs[(wc + ni * 16 + lr) * 32 + lk]);
#pragma unroll
        for (int mi = 0; mi < 4; ++mi)
#pragma unroll
            for (int ni = 0; ni < 4; ++ni)
                acc[mi][ni] = __builtin_amdgcn_mfma_f32_16x16x32_bf16(
                    fa[mi], fb[ni], acc[mi][ni], 0, 0, 0);
    }

    const int rbase = (lane >> 4) * 4;
#pragma unroll
    for (int mi = 0; mi < 4; ++mi)
#pragma unroll
        for (int ni = 0; ni < 4; ++ni) {
            const int col = n0 + wc + ni * 16 + lr;
#pragma unroll
            for (int j = 0; j < 4; ++j) {
                const int row = m0 + wr + mi * 16 + rbase + j;
                C[(size_t)row * N + col] = f2bf(acc[mi][ni][j]);
            }
        }
}

// ---------------------------------------------------------------------------
// 256x256 BK=64 8-wave double-buffered 2-phase bf16 MFMA GEMM (main GEMMs).
// C[M][ldc] = A[M][K] @ B[Nrows][K]^T  (M mult of 256, N covered by grid.y*256,
// K mult of 64). 512 threads = 8 waves (2M x 4N), per-wave output 128x64.
// LDS: 2 x (256x64 A + 256x64 B) bf16 = 128 KiB, double-buffered.
// T2-style swizzle: element col ^= (row&7)<<3, applied on BOTH the per-lane
// global source address (linear global_load_lds dest) and the ds_read side.
// Schedule (T3-minimum): stage(next) -> ds_read+MFMA(cur) -> __syncthreads().
// EPI:   C += Dv[n]*uu[m*DMODEL+n]  (fp32 out)
// OUTBF: store bf16
// ---------------------------------------------------------------------------
template <bool EPI, bool OUTBF>
__global__ __launch_bounds__(512, 2) void gemm256(const ushort_t* __restrict__ A,
                                                  const ushort_t* __restrict__ B,
                                                  void* __restrict__ Cv,
                                                  int M, int K, int ldc,
                                                  const float* __restrict__ uu,
                                                  const float* __restrict__ Dv) {
    __shared__ ushort_t As[2][256 * 64];   // 32 KB each
    __shared__ ushort_t Bs[2][256 * 64];
    const int tid  = threadIdx.x;
    const int lane = tid & 63;
    const int w    = tid >> 6;      // 0..7
    const int wm   = w >> 2;        // 0..1
    const int wn   = w & 3;         // 0..3
    const int m0 = blockIdx.x * 256;
    const int n0 = blockIdx.y * 256;
    const int lr = lane & 15;
    const int lk = (lane >> 4) * 8;

    f32x4 acc[8][4] = {};

    const int sidx0 = tid * 8;      // element index within 256x64 tile, issue q=0

    auto stage = [&](int buf, int k0) {
#pragma unroll
        for (int q = 0; q < 4; ++q) {
            const int idx  = q * 4096 + sidx0;
            const int row  = idx >> 6;
            const int colE = idx & 63;
            const int scol = colE ^ ((row & 7) << 3);   // inverse swizzle on source
            async_cp16(A + (size_t)(m0 + row) * K + k0 + scol,
                       &As[buf][q * 4096 + w * 512]);
            async_cp16(B + (size_t)(n0 + row) * K + k0 + scol,
                       &Bs[buf][q * 4096 + w * 512]);
        }
    };

    const int kIters = K >> 6;
    stage(0, 0);
    __syncthreads();                 // drains vmcnt(0): buf0 ready
    int cur = 0;
    for (int t = 0; t < kIters; ++t) {
        if (t + 1 < kIters) stage(cur ^ 1, (t + 1) << 6);   // prefetch next tile

        bf16x8 fb[4][2];
#pragma unroll
        for (int ni = 0; ni < 4; ++ni)
#pragma unroll
            for (int kk = 0; kk < 2; ++kk) {
                const int row = wn * 64 + ni * 16 + lr;
                const int col = (kk * 32 + lk) ^ ((row & 7) << 3);
                fb[ni][kk] = *reinterpret_cast<const bf16x8*>(&Bs[cur][row * 64 + col]);
            }
#pragma unroll
        for (int mi = 0; mi < 8; ++mi) {
            bf16x8 fa[2];
#pragma unroll
            for (int kk = 0; kk < 2; ++kk) {
                const int row = wm * 128 + mi * 16 + lr;
                const int col = (kk * 32 + lk) ^ ((row & 7) << 3);
                fa[kk] = *reinterpret_cast<const bf16x8*>(&As[cur][row * 64 + col]);
            }
#pragma unroll
            for (int ni = 0; ni < 4; ++ni) {
                acc[mi][ni] = __builtin_amdgcn_mfma_f32_16x16x32_bf16(
                    fa[0], fb[ni][0], acc[mi][ni], 0, 0, 0);
                acc[mi][ni] = __builtin_amdgcn_mfma_f32_16x16x32_bf16(
                    fa[1], fb[ni][1], acc[mi][ni], 0, 0, 0);
            }
        }
        __syncthreads();             // drain prefetch (vmcnt 0) + ds_reads done
        cur ^= 1;
    }

    const int rbase = (lane >> 4) * 4;
#pragma unroll
    for (int mi = 0; mi < 8; ++mi)
#pragma unroll
        for (int ni = 0; ni < 4; ++ni) {
            const int col = n0 + wn * 64 + ni * 16 + lr;
#pragma unroll
            for (int j = 0; j < 4; ++j) {
                const int row = m0 + wm * 128 + mi * 16 + rbase + j;
                float v = acc[mi][ni][j];
                if (EPI) v = fmaf(Dv[col], uu[(size_t)row * DMODEL + col], v);
                if (OUTBF)
                    ((ushort_t*)Cv)[(size_t)row * ldc + col] = f2bf(v);
                else
                    ((float*)Cv)[(size_t)row * ldc + col] = v;
            }
        }
}

// ---------------------------------------------------------------------------
// fp32 -> bf16 (flat, 8 elements/thread)
// ---------------------------------------------------------------------------
__global__ __launch_bounds__(256) void conv_bf16(const float* __restrict__ s,
                                                 ushort_t* __restrict__ d, int n8) {
    const int i = blockIdx.x * 256 + threadIdx.x;
    if (i >= n8) return;
    const float4 a = reinterpret_cast<const float4*>(s)[2 * i];
    const float4 b = reinterpret_cast<const float4*>(s)[2 * i + 1];
    ushort_t o[8] = {f2bf(a.x), f2bf(a.y), f2bf(a.z), f2bf(a.w),
                     f2bf(b.x), f2bf(b.y), f2bf(b.z), f2bf(b.w)};
    reinterpret_cast<bf16x8*>(d)[i] = *reinterpret_cast<bf16x8*>(o);
}

// ---------------------------------------------------------------------------
// Chunked parallel scan, in place on bf16 UHb [bt][NSPEC].
// Re at col kf (0..512); Im at col 512+kf (kf=1..511). kf in {0,512}: real-only.
// fp32 accumulate in registers; bf16 rounding at stores.
// ---------------------------------------------------------------------------
__global__ __launch_bounds__(256) void scan_local(ushort_t* __restrict__ UHb,
                                                  const float* __restrict__ lam) {
    const int gid = blockIdx.x * 256 + threadIdx.x;
    if (gid >= BATCH * NC * KFREQ) return;
    const int kf = gid % KFREQ;
    const int bc = gid / KFREQ;
    const int c = bc & (NC - 1);
    const int b = bc / NC;
    const bool him = (kf != 0 && kf != 512);
    const float lr = lam[kf];
    const float li = him ? lam[512 + kf] : 0.0f;
    ushort_t* base = UHb + ((size_t)(b * SEQLEN + c * TC)) * NSPEC + kf;
    float hr = 0.0f, hi = 0.0f;
    for (int t = 0; t < TC; ++t) {
        const float ur = bf2f(base[(size_t)t * NSPEC]);
        const float ui = him ? bf2f(base[(size_t)t * NSPEC + 512]) : 0.0f;
        const float nr = fmaf(lr, hr, fmaf(-li, hi, ur));
        const float ni = fmaf(lr, hi, fmaf(li, hr, ui));
        base[(size_t)t * NSPEC] = f2bf(nr);
        if (him) base[(size_t)t * NSPEC + 512] = f2bf(ni);
        hr = nr; hi = ni;
    }
}

__global__ __launch_bounds__(256) void scan_carry(const ushort_t* __restrict__ UHb,
                                                  const float* __restrict__ lam,
                                                  float* __restrict__ Ac) {
    const int gid = blockIdx.x * 256 + threadIdx.x;
    if (gid >= BATCH * KFREQ) return;
    const int kf = gid % KFREQ;
    const int b = gid / KFREQ;
    const bool him = (kf != 0 && kf != 512);
    const float lr = lam[kf];
    const float li = him ? lam[512 + kf] : 0.0f;
    float pr = lr, pi = li;          // lambda^64 via 6 squarings
    for (int s = 0; s < 6; ++s) {
        const float nr = pr * pr - pi * pi;
        const float ni = 2.0f * pr * pi;
        pr = nr; pi = ni;
    }
    float er = 0.0f, ei = 0.0f;
    for (int c = 0; c < NC; ++c) {
        const size_t ai = (size_t)(b * NC + c) * KFREQ + kf;
        Ac[ai] = er;
        Ac[(size_t)BATCH * NC * KFREQ + ai] = ei;
        const size_t gi = ((size_t)(b * SEQLEN + c * TC + TC - 1)) * NSPEC + kf;
        const float gr = bf2f(UHb[gi]);
        const float gm = him ? bf2f(UHb[gi + 512]) : 0.0f;
        const float nr = fmaf(pr, er, fmaf(-pi, ei, gr));
        const float ni = fmaf(pr, ei, fmaf(pi, er, gm));
        er = nr; ei = ni;
    }
}

// H_global[tau] = H_local[tau] + lambda^{tau+1} * carry   (in place, bf16)
__global__ __launch_bounds__(256) void scan_apply(ushort_t* __restrict__ UHb,
                                                  const float* __restrict__ lam,
                                                  const float* __restrict__ Ac) {
    const int gid = blockIdx.x * 256 + threadIdx.x;
    if (gid >= BATCH * NC * KFREQ) return;
    const int kf = gid % KFREQ;
    const int bc = gid / KFREQ;
    const int c = bc & (NC - 1);
    const int b = bc / NC;
    if (c == 0) return;                        // carry is zero
    const bool him = (kf != 0 && kf != 512);
    const float er = Ac[gid];
    const float ei = Ac[(size_t)BATCH * NC * KFREQ + gid];
    const float lr = lam[kf];
    const float li = him ? lam[512 + kf] : 0.0f;
    ushort_t* base = UHb + ((size_t)(b * SEQLEN + c * TC)) * NSPEC + kf;
    float pr = lr, pi = li;   // lambda^1
    for (int t = 0; t < TC; ++t) {
        const float hr = bf2f(base[(size_t)t * NSPEC]);
        const float hi = him ? bf2f(base[(size_t)t * NSPEC + 512]) : 0.0f;
        base[(size_t)t * NSPEC] = f2bf(fmaf(pr, er, fmaf(-pi, ei, hr)));
        if (him) base[(size_t)t * NSPEC + 512] = f2bf(fmaf(pr, ei, fmaf(pi, er, hi)));
        const float nr = fmaf(pr, lr, -pi * li);
        const float ni = fmaf(pr, li, pi * lr);
        pr = nr; pi = ni;
    }
}

// ---------------------------------------------------------------------------
extern "C" void kernel_launch(void* const* d_in, const int* in_sizes, int n_in,
                              void* d_out, int out_size, void* d_ws, size_t ws_size,
                              hipStream_t stream) {
    const float* u  = (const float*)d_in[0];  // [B][S][D]
    const float* ap = (const float*)d_in[1];  // [512]
    const float* Bw = (const float*)d_in[2];  // [N][D]
    const float* Cw = (const float*)d_in[3];  // [D][N]
    const float* Dv = (const float*)d_in[4];  // [D]
    float* out = (float*)d_out;               // [B][S][D]

    char* ws = (char*)d_ws;
    size_t off = 0;
    auto carve = [&](size_t bytes) { char* p = ws + off; off += (bytes + 255) & ~(size_t)255; return p; };

    ushort_t* UHb  = (ushort_t*)carve((size_t)BT_ROWS * NSPEC * sizeof(ushort_t));  // 33.6 MB
    ushort_t* ub   = (ushort_t*)carve((size_t)BT_ROWS * DMODEL * sizeof(ushort_t)); // 33.6 MB
    ushort_t* T1b  = (ushort_t*)carve((size_t)NSPEC * DMODEL * sizeof(ushort_t));
    ushort_t* T2b  = (ushort_t*)carve((size_t)NSPEC * DMODEL * sizeof(ushort_t));
    ushort_t* BwTb = (ushort_t*)carve((size_t)DMODEL * DMODEL * sizeof(ushort_t));
    ushort_t* Cwb  = (ushort_t*)carve((size_t)DMODEL * DMODEL * sizeof(ushort_t));
    ushort_t* W1b  = (ushort_t*)carve((size_t)NSPEC * DMODEL * sizeof(ushort_t));
    ushort_t* W2b  = (ushort_t*)carve((size_t)DMODEL * NSPEC * sizeof(ushort_t));
    float*    lam  = (float*)   carve(NSPEC * sizeof(float));
    float*    Ac   = (float*)   carve((size_t)2 * BATCH * NC * KFREQ * sizeof(float));

    // 1) eigenvalues
    compute_lambda<<<1, 1024, 0, stream>>>(ap, lam);

    // 2) trig matrices (bf16) + operand conversions
    gen_Tb<<<NSPEC * DMODEL / 8 / 256, 256, 0, stream>>>(T1b, 0);
    gen_Tb<<<NSPEC * DMODEL / 8 / 256, 256, 0, stream>>>(T2b, 1);
    {
        dim3 g(DMODEL / 64, DMODEL / 64);
        transp_conv<<<g, 256, 0, stream>>>(Bw, BwTb);
    }
    conv_bf16<<<DMODEL * DMODEL / 8 / 256, 256, 0, stream>>>(Cw, Cwb, DMODEL * DMODEL / 8);
    conv_bf16<<<BT_ROWS * (DMODEL / 8) / 256, 256, 0, stream>>>(u, ub, BT_ROWS * (DMODEL / 8));

    // 3) W1b[spec][d] = T1b @ BwTb^T   (128^2 kernel, bf16 out)
    {
        dim3 g(NSPEC / 128, DMODEL / 128);
        gemm128<<<g, 256, 0, stream>>>(T1b, BwTb, W1b, NSPEC, DMODEL, DMODEL);
    }
    // 4) W2b[d][spec] = Cwb @ T2b^T   (128^2 kernel, bf16 out)
    {
        dim3 g(DMODEL / 128, NSPEC / 128);
        gemm128<<<g, 256, 0, stream>>>(Cwb, T2b, W2b, DMODEL, NSPEC, DMODEL);
    }

    // 5) UHb[bt][spec] = ub @ W1b^T   (256^2 2-phase, bf16 out)
    {
        dim3 g(BT_ROWS / 256, NSPEC / 256);
        gemm256<false, true><<<g, 512, 0, stream>>>(ub, W1b, UHb,
            BT_ROWS, DMODEL, NSPEC, nullptr, nullptr);
    }

    // 6) scan over time (in place on bf16): local, carry, apply
    scan_local<<<(BATCH * NC * KFREQ + 255) / 256, 256, 0, stream>>>(UHb, lam);
    scan_carry<<<(BATCH * KFREQ + 255) / 256, 256, 0, stream>>>(UHb, lam, Ac);
    scan_apply<<<(BATCH * NC * KFREQ + 255) / 256, 256, 0, stream>>>(UHb, lam, Ac);

    // 7) y = UHb @ W2b^T + D*u   (256^2 2-phase, fp32 out)
    {
        dim3 g(BT_ROWS / 256, DMODEL / 256);
        gemm256<true, false><<<g, 512, 0, stream>>>(UHb, W2b, out,
            BT_ROWS, NSPEC, DMODEL, u, Dv);
    }
}

// Round 7
// 243.133 us; speedup vs baseline: 1.2194x; 1.0006x over previous
//
#include <hip/hip_runtime.h>
#include <math.h>

// Problem constants
#define BATCH   8
#define SEQLEN  2048
#define DMODEL  1024
#define KFREQ   513        // unique half-spectrum freqs 0..512
#define NSPEC   1024       // exact: 513 Re (cols 0..512) + 511 Im (cols 513..1023, k=1..511)
#define BT_ROWS (BATCH*SEQLEN)   // 16384
#define NC      32         // time chunks for parallel scan
#define TC      64         // chunk length; NC*TC == SEQLEN

static_assert(NC * TC == SEQLEN, "chunking must cover SEQLEN");

typedef __attribute__((ext_vector_type(4))) float f32x4;
typedef __attribute__((ext_vector_type(8))) short bf16x8;   // 8 bf16 in 4 VGPRs
typedef unsigned short ushort_t;

__device__ __forceinline__ ushort_t f2bf(float f) {
    union { float f; unsigned u; } v; v.f = f;
    unsigned r = v.u + 0x7FFFu + ((v.u >> 16) & 1u);   // RNE
    return (ushort_t)(r >> 16);
}
__device__ __forceinline__ float bf2f(ushort_t b) {
    union { unsigned u; float f; } v; v.u = ((unsigned)b) << 16;
    return v.f;
}

__device__ __forceinline__ void async_cp16(const void* g, void* l) {
    __builtin_amdgcn_global_load_lds(
        (const __attribute__((address_space(1))) void*)g,
        (__attribute__((address_space(3))) void*)l, 16, 0, 0);
}

// ---------------------------------------------------------------------------
// lambda_k = (1 - i w)/(1 + i w),  w = Im(FFT(a_full))[k]
// layout: lam[k] = Re, k=0..512;  lam[512+k] = Im, k=1..511.
// Also computes dflag = any(D != 0) for the GEMM-Y epilogue fast path.
// ---------------------------------------------------------------------------
__global__ __launch_bounds__(1024) void compute_lambda(const float* __restrict__ p,
                                                       float* __restrict__ lam,
                                                       const float* __restrict__ Dv,
                                                       int* __restrict__ dflag) {
    __shared__ float stab[1024];
    __shared__ int anyd;
    const int tid = threadIdx.x;
    if (tid == 0) anyd = 0;
    stab[tid] = sinf((float)tid * (6.28318530717958647692f / 1024.0f));
    __syncthreads();
    if (Dv[tid] != 0.0f) anyd = 1;     // benign race, same value
    if (tid < KFREQ) {
        float om = 0.0f;
        for (int j = 1; j <= 511; ++j)
            om = fmaf(p[j - 1], stab[(j * tid) & 1023], om);
        om *= -2.0f;
        const float w2 = om * om;
        const float den = 1.0f + w2;
        lam[tid] = (1.0f - w2) / den;
        if (tid >= 1 && tid <= 511)
            lam[512 + tid] = -2.0f * om / den;
    }
    __syncthreads();
    if (tid == 0) *dflag = anyd;
}

// ---------------------------------------------------------------------------
// Trig matrix in bf16, [NSPEC][DMODEL]:
//   row r in [0,513):     cos(2pi r n/1024) * scale_re
//   row r in [513,1024):  k=r-512 in [1,511];  -sin(2pi k n/1024) * scale_im
// mode 0: scale=1.  mode 1: scale_re = ((r==0||r==512)?1:2)/1024; scale_im = 2/1024.
// ---------------------------------------------------------------------------
__global__ __launch_bounds__(256) void gen_Tb(ushort_t* __restrict__ T, int mode) {
    __shared__ float stab[1024];
    for (int j = threadIdx.x; j < 1024; j += 256)
        stab[j] = sinf((float)j * (6.28318530717958647692f / 1024.0f));
    __syncthreads();

    const int i = blockIdx.x * 256 + threadIdx.x;   // 8 elements per thread
    if (i >= NSPEC * DMODEL / 8) return;
    const int row = i >> 7;
    const int nb  = (i & 127) << 3;

    const bool re = (row < KFREQ);
    const int kf = re ? row : row - 512;            // im: 1..511
    float scale = 1.0f;
    if (mode == 1)
        scale = (re ? ((kf == 0 || kf == 512) ? 1.0f : 2.0f) : 2.0f) / 1024.0f;

    ushort_t o[8];
    int m = (kf * nb) & 1023;
#pragma unroll
    for (int j = 0; j < 8; ++j) {
        const float v = re ? stab[(m + 256) & 1023] : -stab[m];
        o[j] = f2bf(v * scale);
        m = (m + kf) & 1023;
    }
    reinterpret_cast<bf16x8*>(T)[i] = *reinterpret_cast<bf16x8*>(o);
}

// ---------------------------------------------------------------------------
// Transpose-convert: dst[c][r] (bf16, 1024x1024) = src[r][c] (fp32)
// ---------------------------------------------------------------------------
__global__ __launch_bounds__(256) void transp_conv(const float* __restrict__ s,
                                                   ushort_t* __restrict__ d) {
    __shared__ float tile[64][65];
    const int bx = blockIdx.x * 64;
    const int by = blockIdx.y * 64;
    const int lx = threadIdx.x & 63;
    const int ly = threadIdx.x >> 6;
#pragma unroll
    for (int i = 0; i < 16; ++i) {
        const int r = ly + i * 4;
        tile[r][lx] = s[(size_t)(by + r) * DMODEL + bx + lx];
    }
    __syncthreads();
#pragma unroll
    for (int i = 0; i < 16; ++i) {
        const int r = ly + i * 4;
        d[(size_t)(bx + r) * DMODEL + by + lx] = f2bf(tile[lx][r]);
    }
}

// ---------------------------------------------------------------------------
// 128x128 BK=32 bf16 MFMA GEMM — the two small weight-precompute GEMMs.
// C (bf16) [M][N] = A[M][K] @ B[N][K]^T.
// ---------------------------------------------------------------------------
__global__ __launch_bounds__(256) void gemm128(const ushort_t* __restrict__ A,
                                               const ushort_t* __restrict__ B,
                                               ushort_t* __restrict__ C,
                                               int M, int N, int K) {
    __shared__ ushort_t As[128 * 32];
    __shared__ ushort_t Bs[128 * 32];
    const int tid  = threadIdx.x;
    const int lane = tid & 63;
    const int w    = tid >> 6;
    const int m0 = blockIdx.x * 128;
    const int n0 = blockIdx.y * 128;
    const int wr = (w >> 1) * 64;
    const int wc = (w & 1) * 64;

    f32x4 acc[4][4] = {};

    const int pos  = w * 512 + lane * 8;
    const int srow = pos >> 5;
    const int scol = pos & 31;
    const int lr = lane & 15;
    const int lk = (lane >> 4) * 8;

    for (int k0 = 0; k0 < K; k0 += 32) {
        __syncthreads();
        async_cp16(A + (size_t)(m0 + srow)      * K + k0 + scol, As + w * 512);
        async_cp16(A + (size_t)(m0 + srow + 64) * K + k0 + scol, As + 2048 + w * 512);
        async_cp16(B + (size_t)(n0 + srow)      * K + k0 + scol, Bs + w * 512);
        async_cp16(B + (size_t)(n0 + srow + 64) * K + k0 + scol, Bs + 2048 + w * 512);
        __syncthreads();

        bf16x8 fa[4], fb[4];
#pragma unroll
        for (int mi = 0; mi < 4; ++mi)
            fa[mi] = *reinterpret_cast<const bf16x8*>(&As[(wr + mi * 16 + lr) * 32 + lk]);
#pragma unroll
        for (int ni = 0; ni < 4; ++ni)
            fb[ni] = *reinterpret_cast<const bf16x8*>(&Bs[(wc + ni * 16 + lr) * 32 + lk]);
#pragma unroll
        for (int mi = 0; mi < 4; ++mi)
#pragma unroll
            for (int ni = 0; ni < 4; ++ni)
                acc[mi][ni] = __builtin_amdgcn_mfma_f32_16x16x32_bf16(
                    fa[mi], fb[ni], acc[mi][ni], 0, 0, 0);
    }

    const int rbase = (lane >> 4) * 4;
#pragma unroll
    for (int mi = 0; mi < 4; ++mi)
#pragma unroll
        for (int ni = 0; ni < 4; ++ni) {
            const int col = n0 + wc + ni * 16 + lr;
#pragma unroll
            for (int j = 0; j < 4; ++j) {
                const int row = m0 + wr + mi * 16 + rbase + j;
                C[(size_t)row * N + col] = f2bf(acc[mi][ni][j]);
            }
        }
}

// ---------------------------------------------------------------------------
// 256x256 BK=64 8-wave bf16 MFMA GEMM, 4-phase counted-vmcnt schedule (T3+T4+T5).
// C[M][ldc] = A[M][K] @ B[Nrows][K]^T.  512 threads = 8 waves (wm=w>>2, wn=w&3).
// Per-wave C spans BOTH halves in M and N: rows {mh*128 + wm*64 + mi*16},
// cols {nh*128 + wn*32 + ni*16}, so half-tile consumption matches stage order.
// Stage order per tile: A-lo, B-lo, A-hi, B-hi (one half per phase, 2 loads/thr).
// Waits: P0 vmcnt(4), P1/P2 vmcnt(6), P3 none; raw s_barrier (no vmcnt(0) drain
// in the loop). Last tile peeled with vmcnt(4/2/0).
// T2 swizzle: col ^ ((row&7)<<3) on global source + ds_read (involution).
// EPI: if(*dflag) C += Dv[n]*uu[m*DMODEL+n]  (fp32 out). OUTBF: bf16 out.
// ---------------------------------------------------------------------------
template <int MH, int NH>
__device__ __forceinline__ void quad_mfma(f32x4 (&acc)[2][2][4][2],
                                          const bf16x8 (&fa)[4][2],
                                          const bf16x8 (&fb)[2][2]) {
#pragma unroll
    for (int mi = 0; mi < 4; ++mi)
#pragma unroll
        for (int ni = 0; ni < 2; ++ni) {
            acc[MH][NH][mi][ni] = __builtin_amdgcn_mfma_f32_16x16x32_bf16(
                fa[mi][0], fb[ni][0], acc[MH][NH][mi][ni], 0, 0, 0);
            acc[MH][NH][mi][ni] = __builtin_amdgcn_mfma_f32_16x16x32_bf16(
                fa[mi][1], fb[ni][1], acc[MH][NH][mi][ni], 0, 0, 0);
        }
}

__device__ __forceinline__ void load_fa(bf16x8 (&fa)[4][2], const ushort_t* Ab,
                                        int mh, int wm, int lr, int lk) {
#pragma unroll
    for (int mi = 0; mi < 4; ++mi)
#pragma unroll
        for (int kk = 0; kk < 2; ++kk) {
            const int r = mh * 128 + wm * 64 + mi * 16 + lr;
            const int c = (kk * 32 + lk) ^ ((r & 7) << 3);
            fa[mi][kk] = *reinterpret_cast<const bf16x8*>(&Ab[r * 64 + c]);
        }
}
__device__ __forceinline__ void load_fb(bf16x8 (&fb)[2][2], const ushort_t* Bb,
                                        int nh, int wn, int lr, int lk) {
#pragma unroll
    for (int ni = 0; ni < 2; ++ni)
#pragma unroll
        for (int kk = 0; kk < 2; ++kk) {
            const int r = nh * 128 + wn * 32 + ni * 16 + lr;
            const int c = (kk * 32 + lk) ^ ((r & 7) << 3);
            fb[ni][kk] = *reinterpret_cast<const bf16x8*>(&Bb[r * 64 + c]);
        }
}

template <bool EPI, bool OUTBF>
__global__ __launch_bounds__(512, 2) void gemm256(const ushort_t* __restrict__ A,
                                                  const ushort_t* __restrict__ B,
                                                  void* __restrict__ Cv,
                                                  int M, int K, int ldc,
                                                  const float* __restrict__ uu,
                                                  const float* __restrict__ Dv,
                                                  const int* __restrict__ dflag) {
    __shared__ ushort_t As[2][256 * 64];   // 32 KB each
    __shared__ ushort_t Bs[2][256 * 64];
    const int tid  = threadIdx.x;
    const int lane = tid & 63;
    const int w    = tid >> 6;      // 0..7
    const int wm   = w >> 2;        // 0..1
    const int wn   = w & 3;         // 0..3
    const int m0 = blockIdx.x * 256;
    const int n0 = blockIdx.y * 256;
    const int lr = lane & 15;
    const int lk = (lane >> 4) * 8;

    f32x4 acc[2][2][4][2] = {};
    bf16x8 fa[4][2], fb[2][2];

    // stage one half-tile (128 rows of A or B) of K-tile at k0 into buf.
    // half: 0=A rows 0-127, 1=B rows 0-127, 2=A rows 128-255, 3=B rows 128-255.
    auto stage_half = [&](int buf, int k0, int half) {
        const ushort_t* Mat = (half & 1) ? B : A;
        ushort_t* lds = (half & 1) ? &Bs[buf][0] : &As[buf][0];
        const int rb = (half >> 1) * 128;
        const int base_row = ((half & 1) ? n0 : m0) + rb;
#pragma unroll
        for (int li = 0; li < 2; ++li) {
            const int e = li * 4096 + tid * 8;
            const int row = e >> 6;             // 0..127
            const int col = e & 63;
            const int scol = col ^ ((row & 7) << 3);   // inverse swizzle on source
            async_cp16(Mat + (size_t)(base_row + row) * K + k0 + scol,
                       lds + rb * 64 + li * 4096 + (w << 9));
        }
    };

    const int nt = K >> 6;
    // prologue: stage tile 0 fully (8 loads outstanding)
    stage_half(0, 0, 0); stage_half(0, 0, 1);
    stage_half(0, 0, 2); stage_half(0, 0, 3);

    int cur = 0;
    for (int t = 0; t < nt - 1; ++t) {
        const int kn = (t + 1) << 6;
        const int nxt = cur ^ 1;
        // P0: quadrant (0,0) — needs A-lo(t), B-lo(t) = oldest 4 loads
        asm volatile("s_waitcnt vmcnt(4)" ::: "memory");
        __builtin_amdgcn_s_barrier();
        stage_half(nxt, kn, 0);
        load_fa(fa, &As[cur][0], 0, wm, lr, lk);
        load_fb(fb, &Bs[cur][0], 0, wn, lr, lk);
        __builtin_amdgcn_s_setprio(1);
        quad_mfma<0, 0>(acc, fa, fb);
        __builtin_amdgcn_s_setprio(0);
        // P1: quadrant (1,0) — needs A-hi(t)
        stage_half(nxt, kn, 1);
        asm volatile("s_waitcnt vmcnt(6)" ::: "memory");
        __builtin_amdgcn_s_barrier();
        load_fa(fa, &As[cur][0], 1, wm, lr, lk);
        __builtin_amdgcn_s_setprio(1);
        quad_mfma<1, 0>(acc, fa, fb);
        __builtin_amdgcn_s_setprio(0);
        // P2: quadrant (1,1) — needs B-hi(t)
        stage_half(nxt, kn, 2);
        asm volatile("s_waitcnt vmcnt(6)" ::: "memory");
        __builtin_amdgcn_s_barrier();
        load_fb(fb, &Bs[cur][0], 1, wn, lr, lk);
        __builtin_amdgcn_s_setprio(1);
        quad_mfma<1, 1>(acc, fa, fb);
        __builtin_amdgcn_s_setprio(0);
        // P3: quadrant (0,1) — reload A-lo(t), reuse B-hi; no wait/barrier
        stage_half(nxt, kn, 3);
        load_fa(fa, &As[cur][0], 0, wm, lr, lk);
        __builtin_amdgcn_s_setprio(1);
        quad_mfma<0, 1>(acc, fa, fb);
        __builtin_amdgcn_s_setprio(0);
        cur = nxt;
    }
    // epilogue tile (no stages; tightened waits)
    asm volatile("s_waitcnt vmcnt(4)" ::: "memory");
    __builtin_amdgcn_s_barrier();
    load_fa(fa, &As[cur][0], 0, wm, lr, lk);
    load_fb(fb, &Bs[cur][0], 0, wn, lr, lk);
    __builtin_amdgcn_s_setprio(1);
    quad_mfma<0, 0>(acc, fa, fb);
    __builtin_amdgcn_s_setprio(0);
    asm volatile("s_waitcnt vmcnt(2)" ::: "memory");
    __builtin_amdgcn_s_barrier();
    load_fa(fa, &As[cur][0], 1, wm, lr, lk);
    __builtin_amdgcn_s_setprio(1);
    quad_mfma<1, 0>(acc, fa, fb);
    __builtin_amdgcn_s_setprio(0);
    asm volatile("s_waitcnt vmcnt(0)" ::: "memory");
    __builtin_amdgcn_s_barrier();
    load_fb(fb, &Bs[cur][0], 1, wn, lr, lk);
    __builtin_amdgcn_s_setprio(1);
    quad_mfma<1, 1>(acc, fa, fb);
    __builtin_amdgcn_s_setprio(0);
    load_fa(fa, &As[cur][0], 0, wm, lr, lk);
    __builtin_amdgcn_s_setprio(1);
    quad_mfma<0, 1>(acc, fa, fb);
    __builtin_amdgcn_s_setprio(0);

    // C write
    const int rbase = (lane >> 4) * 4;
    const bool du = EPI && (*dflag != 0);
#pragma unroll
    for (int mh = 0; mh < 2; ++mh)
#pragma unroll
        for (int nh = 0; nh < 2; ++nh)
#pragma unroll
            for (int mi = 0; mi < 4; ++mi)
#pragma unroll
                for (int ni = 0; ni < 2; ++ni) {
                    const int col = n0 + nh * 128 + wn * 32 + ni * 16 + lr;
#pragma unroll
                    for (int j = 0; j < 4; ++j) {
                        const int row = m0 + mh * 128 + wm * 64 + mi * 16 + rbase + j;
                        float v = acc[mh][nh][mi][ni][j];
                        if (EPI && du)
                            v = fmaf(Dv[col], uu[(size_t)row * DMODEL + col], v);
                        if (OUTBF)
                            ((ushort_t*)Cv)[(size_t)row * ldc + col] = f2bf(v);
                        else
                            ((float*)Cv)[(size_t)row * ldc + col] = v;
                    }
                }
}

// ---------------------------------------------------------------------------
// fp32 -> bf16 (flat, 8 elements/thread)
// ---------------------------------------------------------------------------
__global__ __launch_bounds__(256) void conv_bf16(const float* __restrict__ s,
                                                 ushort_t* __restrict__ d, int n8) {
    const int i = blockIdx.x * 256 + threadIdx.x;
    if (i >= n8) return;
    const float4 a = reinterpret_cast<const float4*>(s)[2 * i];
    const float4 b = reinterpret_cast<const float4*>(s)[2 * i + 1];
    ushort_t o[8] = {f2bf(a.x), f2bf(a.y), f2bf(a.z), f2bf(a.w),
                     f2bf(b.x), f2bf(b.y), f2bf(b.z), f2bf(b.w)};
    reinterpret_cast<bf16x8*>(d)[i] = *reinterpret_cast<bf16x8*>(o);
}

// ---------------------------------------------------------------------------
// Chunked parallel scan, in place on bf16 UHb [bt][NSPEC].
// Re at col kf (0..512); Im at col 512+kf (kf=1..511). kf in {0,512}: real-only.
// ---------------------------------------------------------------------------
__global__ __launch_bounds__(256) void scan_local(ushort_t* __restrict__ UHb,
                                                  const float* __restrict__ lam) {
    const int gid = blockIdx.x * 256 + threadIdx.x;
    if (gid >= BATCH * NC * KFREQ) return;
    const int kf = gid % KFREQ;
    const int bc = gid / KFREQ;
    const int c = bc & (NC - 1);
    const int b = bc / NC;
    const bool him = (kf != 0 && kf != 512);
    const float lr = lam[kf];
    const float li = him ? lam[512 + kf] : 0.0f;
    ushort_t* base = UHb + ((size_t)(b * SEQLEN + c * TC)) * NSPEC + kf;
    float hr = 0.0f, hi = 0.0f;
    for (int t = 0; t < TC; ++t) {
        const float ur = bf2f(base[(size_t)t * NSPEC]);
        const float ui = him ? bf2f(base[(size_t)t * NSPEC + 512]) : 0.0f;
        const float nr = fmaf(lr, hr, fmaf(-li, hi, ur));
        const float ni = fmaf(lr, hi, fmaf(li, hr, ui));
        base[(size_t)t * NSPEC] = f2bf(nr);
        if (him) base[(size_t)t * NSPEC + 512] = f2bf(ni);
        hr = nr; hi = ni;
    }
}

__global__ __launch_bounds__(256) void scan_carry(const ushort_t* __restrict__ UHb,
                                                  const float* __restrict__ lam,
                                                  float* __restrict__ Ac) {
    const int gid = blockIdx.x * 256 + threadIdx.x;
    if (gid >= BATCH * KFREQ) return;
    const int kf = gid % KFREQ;
    const int b = gid / KFREQ;
    const bool him = (kf != 0 && kf != 512);
    const float lr = lam[kf];
    const float li = him ? lam[512 + kf] : 0.0f;
    float pr = lr, pi = li;          // lambda^64 via 6 squarings
    for (int s = 0; s < 6; ++s) {
        const float nr = pr * pr - pi * pi;
        const float ni = 2.0f * pr * pi;
        pr = nr; pi = ni;
    }
    float er = 0.0f, ei = 0.0f;
    for (int c = 0; c < NC; ++c) {
        const size_t ai = (size_t)(b * NC + c) * KFREQ + kf;
        Ac[ai] = er;
        Ac[(size_t)BATCH * NC * KFREQ + ai] = ei;
        const size_t gi = ((size_t)(b * SEQLEN + c * TC + TC - 1)) * NSPEC + kf;
        const float gr = bf2f(UHb[gi]);
        const float gm = him ? bf2f(UHb[gi + 512]) : 0.0f;
        const float nr = fmaf(pr, er, fmaf(-pi, ei, gr));
        const float ni = fmaf(pr, ei, fmaf(pi, er, gm));
        er = nr; ei = ni;
    }
}

__global__ __launch_bounds__(256) void scan_apply(ushort_t* __restrict__ UHb,
                                                  const float* __restrict__ lam,
                                                  const float* __restrict__ Ac) {
    const int gid = blockIdx.x * 256 + threadIdx.x;
    if (gid >= BATCH * NC * KFREQ) return;
    const int kf = gid % KFREQ;
    const int bc = gid / KFREQ;
    const int c = bc & (NC - 1);
    const int b = bc / NC;
    if (c == 0) return;                        // carry is zero
    const bool him = (kf != 0 && kf != 512);
    const float er = Ac[gid];
    const float ei = Ac[(size_t)BATCH * NC * KFREQ + gid];
    const float lr = lam[kf];
    const float li = him ? lam[512 + kf] : 0.0f;
    ushort_t* base = UHb + ((size_t)(b * SEQLEN + c * TC)) * NSPEC + kf;
    float pr = lr, pi = li;   // lambda^1
    for (int t = 0; t < TC; ++t) {
        const float hr = bf2f(base[(size_t)t * NSPEC]);
        const float hi = him ? bf2f(base[(size_t)t * NSPEC + 512]) : 0.0f;
        base[(size_t)t * NSPEC] = f2bf(fmaf(pr, er, fmaf(-pi, ei, hr)));
        if (him) base[(size_t)t * NSPEC + 512] = f2bf(fmaf(pr, ei, fmaf(pi, er, hi)));
        const float nr = fmaf(pr, lr, -pi * li);
        const float ni = fmaf(pr, li, pi * lr);
        pr = nr; pi = ni;
    }
}

// ---------------------------------------------------------------------------
extern "C" void kernel_launch(void* const* d_in, const int* in_sizes, int n_in,
                              void* d_out, int out_size, void* d_ws, size_t ws_size,
                              hipStream_t stream) {
    const float* u  = (const float*)d_in[0];  // [B][S][D]
    const float* ap = (const float*)d_in[1];  // [512]
    const float* Bw = (const float*)d_in[2];  // [N][D]
    const float* Cw = (const float*)d_in[3];  // [D][N]
    const float* Dv = (const float*)d_in[4];  // [D]
    float* out = (float*)d_out;               // [B][S][D]

    char* ws = (char*)d_ws;
    size_t off = 0;
    auto carve = [&](size_t bytes) { char* p = ws + off; off += (bytes + 255) & ~(size_t)255; return p; };

    ushort_t* UHb  = (ushort_t*)carve((size_t)BT_ROWS * NSPEC * sizeof(ushort_t));  // 33.6 MB
    ushort_t* ub   = (ushort_t*)carve((size_t)BT_ROWS * DMODEL * sizeof(ushort_t)); // 33.6 MB
    ushort_t* T1b  = (ushort_t*)carve((size_t)NSPEC * DMODEL * sizeof(ushort_t));
    ushort_t* T2b  = (ushort_t*)carve((size_t)NSPEC * DMODEL * sizeof(ushort_t));
    ushort_t* BwTb = (ushort_t*)carve((size_t)DMODEL * DMODEL * sizeof(ushort_t));
    ushort_t* Cwb  = (ushort_t*)carve((size_t)DMODEL * DMODEL * sizeof(ushort_t));
    ushort_t* W1b  = (ushort_t*)carve((size_t)NSPEC * DMODEL * sizeof(ushort_t));
    ushort_t* W2b  = (ushort_t*)carve((size_t)DMODEL * NSPEC * sizeof(ushort_t));
    float*    lam  = (float*)   carve(NSPEC * sizeof(float));
    int*      dflag= (int*)     carve(sizeof(int));
    float*    Ac   = (float*)   carve((size_t)2 * BATCH * NC * KFREQ * sizeof(float));

    // 1) eigenvalues + D flag
    compute_lambda<<<1, 1024, 0, stream>>>(ap, lam, Dv, dflag);

    // 2) trig matrices (bf16) + operand conversions
    gen_Tb<<<NSPEC * DMODEL / 8 / 256, 256, 0, stream>>>(T1b, 0);
    gen_Tb<<<NSPEC * DMODEL / 8 / 256, 256, 0, stream>>>(T2b, 1);
    {
        dim3 g(DMODEL / 64, DMODEL / 64);
        transp_conv<<<g, 256, 0, stream>>>(Bw, BwTb);
    }
    conv_bf16<<<DMODEL * DMODEL / 8 / 256, 256, 0, stream>>>(Cw, Cwb, DMODEL * DMODEL / 8);
    conv_bf16<<<BT_ROWS * (DMODEL / 8) / 256, 256, 0, stream>>>(u, ub, BT_ROWS * (DMODEL / 8));

    // 3) W1b[spec][d] = T1b @ BwTb^T
    {
        dim3 g(NSPEC / 128, DMODEL / 128);
        gemm128<<<g, 256, 0, stream>>>(T1b, BwTb, W1b, NSPEC, DMODEL, DMODEL);
    }
    // 4) W2b[d][spec] = Cwb @ T2b^T
    {
        dim3 g(DMODEL / 128, NSPEC / 128);
        gemm128<<<g, 256, 0, stream>>>(Cwb, T2b, W2b, DMODEL, NSPEC, DMODEL);
    }

    // 5) UHb[bt][spec] = ub @ W1b^T   (256^2 4-phase, bf16 out)
    {
        dim3 g(BT_ROWS / 256, NSPEC / 256);
        gemm256<false, true><<<g, 512, 0, stream>>>(ub, W1b, UHb,
            BT_ROWS, DMODEL, NSPEC, nullptr, nullptr, dflag);
    }

    // 6) scan over time (in place on bf16): local, carry, apply
    scan_local<<<(BATCH * NC * KFREQ + 255) / 256, 256, 0, stream>>>(UHb, lam);
    scan_carry<<<(BATCH * KFREQ + 255) / 256, 256, 0, stream>>>(UHb, lam, Ac);
    scan_apply<<<(BATCH * NC * KFREQ + 255) / 256, 256, 0, stream>>>(UHb, lam, Ac);

    // 7) y = UHb @ W2b^T + D*u   (256^2 4-phase, fp32 out)
    {
        dim3 g(BT_ROWS / 256, DMODEL / 256);
        gemm256<true, false><<<g, 512, 0, stream>>>(UHb, W2b, out,
            BT_ROWS, NSPEC, DMODEL, u, Dv, dflag);
    }
}

// Round 8
// 235.314 us; speedup vs baseline: 1.2599x; 1.0332x over previous
//
#include <hip/hip_runtime.h>
#include <math.h>

// Problem constants
#define BATCH   8
#define SEQLEN  2048
#define DMODEL  1024
#define KFREQ   513        // unique half-spectrum freqs 0..512
#define NSPEC   1024       // exact: 513 Re (cols 0..512) + 511 Im (cols 513..1023, k=1..511)
#define BT_ROWS (BATCH*SEQLEN)   // 16384
#define NC      32         // time chunks for parallel scan
#define TC      64         // chunk length; NC*TC == SEQLEN

static_assert(NC * TC == SEQLEN, "chunking must cover SEQLEN");

typedef __attribute__((ext_vector_type(4))) float f32x4;
typedef __attribute__((ext_vector_type(8))) short bf16x8;   // 8 bf16 in 4 VGPRs
typedef unsigned short ushort_t;

__device__ __forceinline__ ushort_t f2bf(float f) {
    union { float f; unsigned u; } v; v.f = f;
    unsigned r = v.u + 0x7FFFu + ((v.u >> 16) & 1u);   // RNE
    return (ushort_t)(r >> 16);
}
__device__ __forceinline__ float bf2f(ushort_t b) {
    union { unsigned u; float f; } v; v.u = ((unsigned)b) << 16;
    return v.f;
}

__device__ __forceinline__ void async_cp16(const void* g, void* l) {
    __builtin_amdgcn_global_load_lds(
        (const __attribute__((address_space(1))) void*)g,
        (__attribute__((address_space(3))) void*)l, 16, 0, 0);
}

#define BAR()   __builtin_amdgcn_s_barrier()
#define PRIO1() __builtin_amdgcn_s_setprio(1)
#define PRIO0() __builtin_amdgcn_s_setprio(0)
#define LGKM0() asm volatile("s_waitcnt lgkmcnt(0)" ::: "memory")
#define LGKM8() asm volatile("s_waitcnt lgkmcnt(8)" ::: "memory")
#define VM6()   asm volatile("s_waitcnt vmcnt(6)" ::: "memory")
#define VM0()   asm volatile("s_waitcnt vmcnt(0)" ::: "memory")

// ---------------------------------------------------------------------------
// lambda_k = (1 - i w)/(1 + i w),  w = Im(FFT(a_full))[k]
// layout: lam[k] = Re, k=0..512;  lam[512+k] = Im, k=1..511.
// Also computes dflag = any(D != 0) for the GEMM-Y epilogue fast path.
// ---------------------------------------------------------------------------
__global__ __launch_bounds__(1024) void compute_lambda(const float* __restrict__ p,
                                                       float* __restrict__ lam,
                                                       const float* __restrict__ Dv,
                                                       int* __restrict__ dflag) {
    __shared__ float stab[1024];
    __shared__ int anyd;
    const int tid = threadIdx.x;
    if (tid == 0) anyd = 0;
    stab[tid] = sinf((float)tid * (6.28318530717958647692f / 1024.0f));
    __syncthreads();
    if (Dv[tid] != 0.0f) anyd = 1;     // benign race, same value
    if (tid < KFREQ) {
        float om = 0.0f;
        for (int j = 1; j <= 511; ++j)
            om = fmaf(p[j - 1], stab[(j * tid) & 1023], om);
        om *= -2.0f;
        const float w2 = om * om;
        const float den = 1.0f + w2;
        lam[tid] = (1.0f - w2) / den;
        if (tid >= 1 && tid <= 511)
            lam[512 + tid] = -2.0f * om / den;
    }
    __syncthreads();
    if (tid == 0) *dflag = anyd;
}

// ---------------------------------------------------------------------------
// Trig matrix in bf16, [NSPEC][DMODEL]:
//   row r in [0,513):     cos(2pi r n/1024) * scale_re
//   row r in [513,1024):  k=r-512 in [1,511];  -sin(2pi k n/1024) * scale_im
// mode 0: scale=1.  mode 1: scale_re = ((r==0||r==512)?1:2)/1024; scale_im = 2/1024.
// ---------------------------------------------------------------------------
__global__ __launch_bounds__(256) void gen_Tb(ushort_t* __restrict__ T, int mode) {
    __shared__ float stab[1024];
    for (int j = threadIdx.x; j < 1024; j += 256)
        stab[j] = sinf((float)j * (6.28318530717958647692f / 1024.0f));
    __syncthreads();

    const int i = blockIdx.x * 256 + threadIdx.x;   // 8 elements per thread
    if (i >= NSPEC * DMODEL / 8) return;
    const int row = i >> 7;
    const int nb  = (i & 127) << 3;

    const bool re = (row < KFREQ);
    const int kf = re ? row : row - 512;            // im: 1..511
    float scale = 1.0f;
    if (mode == 1)
        scale = (re ? ((kf == 0 || kf == 512) ? 1.0f : 2.0f) : 2.0f) / 1024.0f;

    ushort_t o[8];
    int m = (kf * nb) & 1023;
#pragma unroll
    for (int j = 0; j < 8; ++j) {
        const float v = re ? stab[(m + 256) & 1023] : -stab[m];
        o[j] = f2bf(v * scale);
        m = (m + kf) & 1023;
    }
    reinterpret_cast<bf16x8*>(T)[i] = *reinterpret_cast<bf16x8*>(o);
}

// ---------------------------------------------------------------------------
// Transpose-convert: dst[c][r] (bf16, 1024x1024) = src[r][c] (fp32)
// ---------------------------------------------------------------------------
__global__ __launch_bounds__(256) void transp_conv(const float* __restrict__ s,
                                                   ushort_t* __restrict__ d) {
    __shared__ float tile[64][65];
    const int bx = blockIdx.x * 64;
    const int by = blockIdx.y * 64;
    const int lx = threadIdx.x & 63;
    const int ly = threadIdx.x >> 6;
#pragma unroll
    for (int i = 0; i < 16; ++i) {
        const int r = ly + i * 4;
        tile[r][lx] = s[(size_t)(by + r) * DMODEL + bx + lx];
    }
    __syncthreads();
#pragma unroll
    for (int i = 0; i < 16; ++i) {
        const int r = ly + i * 4;
        d[(size_t)(bx + r) * DMODEL + by + lx] = f2bf(tile[lx][r]);
    }
}

// ---------------------------------------------------------------------------
// 128x128 BK=32 bf16 MFMA GEMM — the two small weight-precompute GEMMs.
// C (bf16) [M][N] = A[M][K] @ B[N][K]^T.
// ---------------------------------------------------------------------------
__global__ __launch_bounds__(256) void gemm128(const ushort_t* __restrict__ A,
                                               const ushort_t* __restrict__ B,
                                               ushort_t* __restrict__ C,
                                               int M, int N, int K) {
    __shared__ ushort_t As[128 * 32];
    __shared__ ushort_t Bs[128 * 32];
    const int tid  = threadIdx.x;
    const int lane = tid & 63;
    const int w    = tid >> 6;
    const int m0 = blockIdx.x * 128;
    const int n0 = blockIdx.y * 128;
    const int wr = (w >> 1) * 64;
    const int wc = (w & 1) * 64;

    f32x4 acc[4][4] = {};

    const int pos  = w * 512 + lane * 8;
    const int srow = pos >> 5;
    const int scol = pos & 31;
    const int lr = lane & 15;
    const int lk = (lane >> 4) * 8;

    for (int k0 = 0; k0 < K; k0 += 32) {
        __syncthreads();
        async_cp16(A + (size_t)(m0 + srow)      * K + k0 + scol, As + w * 512);
        async_cp16(A + (size_t)(m0 + srow + 64) * K + k0 + scol, As + 2048 + w * 512);
        async_cp16(B + (size_t)(n0 + srow)      * K + k0 + scol, Bs + w * 512);
        async_cp16(B + (size_t)(n0 + srow + 64) * K + k0 + scol, Bs + 2048 + w * 512);
        __syncthreads();

        bf16x8 fa[4], fb[4];
#pragma unroll
        for (int mi = 0; mi < 4; ++mi)
            fa[mi] = *reinterpret_cast<const bf16x8*>(&As[(wr + mi * 16 + lr) * 32 + lk]);
#pragma unroll
        for (int ni = 0; ni < 4; ++ni)
            fb[ni] = *reinterpret_cast<const bf16x8*>(&Bs[(wc + ni * 16 + lr) * 32 + lk]);
#pragma unroll
        for (int mi = 0; mi < 4; ++mi)
#pragma unroll
            for (int ni = 0; ni < 4; ++ni)
                acc[mi][ni] = __builtin_amdgcn_mfma_f32_16x16x32_bf16(
                    fa[mi], fb[ni], acc[mi][ni], 0, 0, 0);
    }

    const int rbase = (lane >> 4) * 4;
#pragma unroll
    for (int mi = 0; mi < 4; ++mi)
#pragma unroll
        for (int ni = 0; ni < 4; ++ni) {
            const int col = n0 + wc + ni * 16 + lr;
#pragma unroll
            for (int j = 0; j < 4; ++j) {
                const int row = m0 + wr + mi * 16 + rbase + j;
                C[(size_t)row * N + col] = f2bf(acc[mi][ni][j]);
            }
        }
}

// ---------------------------------------------------------------------------
// 256x256 8-wave bf16 MFMA GEMM — m201-style 8-phase schedule.
// C[M][ldc] = A[M][K] @ B[Nrows][K]^T.  2 K-tiles (BK=64) per iteration,
// LDS [2 buf][2 half][128][64] per matrix (128 KiB total), buffer = tile&1.
// Per phase: {ds_read subtile, stage 1 half-tile (2 gloads), [lgkm hint],
//             barrier, lgkmcnt(0), setprio(1) 16 MFMA setprio(0), barrier}.
// vmcnt(6) only at P4/P8 (3 half-tiles in flight). Trailing barrier makes each
// stage-issue later than ALL waves' last reads of the slot (WAR safety).
// Reads per tile: P1 12 (fa-lo+fbl), P2 4 (fbh), P3 8 (fa-hi), P4 0 = 24 min.
// T2 swizzle: col ^ ((row&7)<<3) on global source + ds_read (involution).
// EPI: if(*dflag) C += Dv[n]*uu[m*DMODEL+n]  (fp32 out). OUTBF: bf16 out.
// ---------------------------------------------------------------------------
template <int MH, int NH>
__device__ __forceinline__ void quad_mfma(f32x4 (&acc)[2][2][4][2],
                                          const bf16x8 (&fa)[4][2],
                                          const bf16x8 (&fb)[2][2]) {
#pragma unroll
    for (int mi = 0; mi < 4; ++mi)
#pragma unroll
        for (int ni = 0; ni < 2; ++ni) {
            acc[MH][NH][mi][ni] = __builtin_amdgcn_mfma_f32_16x16x32_bf16(
                fa[mi][0], fb[ni][0], acc[MH][NH][mi][ni], 0, 0, 0);
            acc[MH][NH][mi][ni] = __builtin_amdgcn_mfma_f32_16x16x32_bf16(
                fa[mi][1], fb[ni][1], acc[MH][NH][mi][ni], 0, 0, 0);
        }
}

__device__ __forceinline__ void ld_fa(bf16x8 (&fa)[4][2], const ushort_t* hb,
                                      int wm, int lr, int c0, int c1) {
#pragma unroll
    for (int mi = 0; mi < 4; ++mi) {
        const ushort_t* p = hb + (wm * 64 + mi * 16 + lr) * 64;
        fa[mi][0] = *reinterpret_cast<const bf16x8*>(p + c0);
        fa[mi][1] = *reinterpret_cast<const bf16x8*>(p + c1);
    }
}
__device__ __forceinline__ void ld_fb(bf16x8 (&fb)[2][2], const ushort_t* hb,
                                      int wn, int lr, int c0, int c1) {
#pragma unroll
    for (int ni = 0; ni < 2; ++ni) {
        const ushort_t* p = hb + (wn * 32 + ni * 16 + lr) * 64;
        fb[ni][0] = *reinterpret_cast<const bf16x8*>(p + c0);
        fb[ni][1] = *reinterpret_cast<const bf16x8*>(p + c1);
    }
}

template <bool EPI, bool OUTBF>
__global__ __launch_bounds__(512, 2) void gemm256(const ushort_t* __restrict__ A,
                                                  const ushort_t* __restrict__ B,
                                                  void* __restrict__ Cv,
                                                  int M, int K, int ldc,
                                                  const float* __restrict__ uu,
                                                  const float* __restrict__ Dv,
                                                  const int* __restrict__ dflag) {
    __shared__ ushort_t As[2][2][128][64];   // [buf][half][row][col] 64 KB
    __shared__ ushort_t Bs[2][2][128][64];
    const int tid  = threadIdx.x;
    const int lane = tid & 63;
    const int w    = tid >> 6;      // 0..7
    const int wm   = w >> 2;        // 0..1
    const int wn   = w & 3;         // 0..3
    const int m0 = blockIdx.x * 256;
    const int n0 = blockIdx.y * 256;
    const int lr = lane & 15;
    const int lk = (lane >> 4) * 8;
    const int xv = (lr & 7) << 3;
    const int c0 = lk ^ xv;
    const int c1 = (32 + lk) ^ xv;

    const int rA = tid >> 3;                             // staging row 0..63
    const int cS = ((tid & 7) << 3) ^ ((rA & 7) << 3);   // pre-swizzled src col
    const int ldsOff = w << 9;                           // wave-uniform elems

    f32x4 acc[2][2][4][2] = {};
    bf16x8 fa[4][2], fbl[2][2], fbh[2][2];

    auto stA = [&](int buf, int half, int k) {
#pragma unroll
        for (int li = 0; li < 2; ++li)
            async_cp16(A + (size_t)(m0 + half * 128 + li * 64 + rA) * K + k + cS,
                       &As[buf][half][0][0] + li * 4096 + ldsOff);
    };
    auto stB = [&](int buf, int half, int k) {
#pragma unroll
        for (int li = 0; li < 2; ++li)
            async_cp16(B + (size_t)(n0 + half * 128 + li * 64 + rA) * K + k + cS,
                       &Bs[buf][half][0][0] + li * 4096 + ldsOff);
    };

    // prologue: tile0 fully, tile1 minus A-hi (staged at P1 of iter 0)
    stA(0, 0, 0); stB(0, 0, 0); stB(0, 1, 0); stA(0, 1, 0);
    stA(1, 0, 64); stB(1, 0, 64); stB(1, 1, 64);
    VM6();            // oldest 8 loads (= all of tile0) landed
    BAR();

    const int niter = K >> 7;       // 2 tiles per iteration
#pragma unroll 1
    for (int t = 0; t < niter - 1; ++t) {
        const int kb1 = (t << 7) + 64;      // tile 2t+1
        const int kn  = (t + 1) << 7;       // tile 2t+2
        const int kn2 = kn + 64;            // tile 2t+3
        // P1: quad (0,0) of tile 2t
        ld_fa(fa, &As[0][0][0][0], wm, lr, c0, c1);
        ld_fb(fbl, &Bs[0][0][0][0], wn, lr, c0, c1);
        stA(1, 1, kb1);
        LGKM8();
        BAR(); LGKM0();
        PRIO1(); quad_mfma<0, 0>(acc, fa, fbl); PRIO0();
        BAR();
        // P2: quad (0,1)
        ld_fb(fbh, &Bs[0][1][0][0], wn, lr, c0, c1);
        stA(0, 0, kn);
        BAR(); LGKM0();
        PRIO1(); quad_mfma<0, 1>(acc, fa, fbh); PRIO0();
        BAR();
        // P3: quad (1,1)
        ld_fa(fa, &As[0][1][0][0], wm, lr, c0, c1);
        stB(0, 0, kn);
        BAR(); LGKM0();
        PRIO1(); quad_mfma<1, 1>(acc, fa, fbh); PRIO0();
        BAR();
        // P4: quad (1,0)  — no reads; counted vmcnt
        stB(0, 1, kn);
        VM6();
        BAR();
        PRIO1(); quad_mfma<1, 0>(acc, fa, fbl); PRIO0();
        BAR();
        // P5: quad (0,0) of tile 2t+1
        ld_fa(fa, &As[1][0][0][0], wm, lr, c0, c1);
        ld_fb(fbl, &Bs[1][0][0][0], wn, lr, c0, c1);
        stA(0, 1, kn);
        LGKM8();
        BAR(); LGKM0();
        PRIO1(); quad_mfma<0, 0>(acc, fa, fbl); PRIO0();
        BAR();
        // P6: quad (0,1)
        ld_fb(fbh, &Bs[1][1][0][0], wn, lr, c0, c1);
        stA(1, 0, kn2);
        BAR(); LGKM0();
        PRIO1(); quad_mfma<0, 1>(acc, fa, fbh); PRIO0();
        BAR();
        // P7: quad (1,1)
        ld_fa(fa, &As[1][1][0][0], wm, lr, c0, c1);
        stB(1, 0, kn2);
        BAR(); LGKM0();
        PRIO1(); quad_mfma<1, 1>(acc, fa, fbh); PRIO0();
        BAR();
        // P8: quad (1,0)
        stB(1, 1, kn2);
        VM6();
        BAR();
        PRIO1(); quad_mfma<1, 0>(acc, fa, fbl); PRIO0();
        BAR();
    }
    // ---- epilogue iteration (tiles 2*niter-2, 2*niter-1): only P1 stages ----
    {
        const int kb1 = ((niter - 1) << 7) + 64;
        // P1
        ld_fa(fa, &As[0][0][0][0], wm, lr, c0, c1);
        ld_fb(fbl, &Bs[0][0][0][0], wn, lr, c0, c1);
        stA(1, 1, kb1);
        LGKM8();
        BAR(); LGKM0();
        PRIO1(); quad_mfma<0, 0>(acc, fa, fbl); PRIO0();
        BAR();
        // P2
        ld_fb(fbh, &Bs[0][1][0][0], wn, lr, c0, c1);
        BAR(); LGKM0();
        PRIO1(); quad_mfma<0, 1>(acc, fa, fbh); PRIO0();
        BAR();
        // P3
        ld_fa(fa, &As[0][1][0][0], wm, lr, c0, c1);
        BAR(); LGKM0();
        PRIO1(); quad_mfma<1, 1>(acc, fa, fbh); PRIO0();
        BAR();
        // P4: drain everything (covers P1's stage + prior iter's tail)
        VM0();
        BAR();
        PRIO1(); quad_mfma<1, 0>(acc, fa, fbl); PRIO0();
        BAR();
        // P5
        ld_fa(fa, &As[1][0][0][0], wm, lr, c0, c1);
        ld_fb(fbl, &Bs[1][0][0][0], wn, lr, c0, c1);
        BAR(); LGKM0();
        PRIO1(); quad_mfma<0, 0>(acc, fa, fbl); PRIO0();
        BAR();
        // P6
        ld_fb(fbh, &Bs[1][1][0][0], wn, lr, c0, c1);
        BAR(); LGKM0();
        PRIO1(); quad_mfma<0, 1>(acc, fa, fbh); PRIO0();
        BAR();
        // P7
        ld_fa(fa, &As[1][1][0][0], wm, lr, c0, c1);
        BAR(); LGKM0();
        PRIO1(); quad_mfma<1, 1>(acc, fa, fbh); PRIO0();
        BAR();
        // P8
        PRIO1(); quad_mfma<1, 0>(acc, fa, fbl); PRIO0();
    }

    // C write
    const int rbase = (lane >> 4) * 4;
    const bool du = EPI && (*dflag != 0);
#pragma unroll
    for (int mh = 0; mh < 2; ++mh)
#pragma unroll
        for (int nh = 0; nh < 2; ++nh)
#pragma unroll
            for (int mi = 0; mi < 4; ++mi)
#pragma unroll
                for (int ni = 0; ni < 2; ++ni) {
                    const int col = n0 + nh * 128 + wn * 32 + ni * 16 + lr;
#pragma unroll
                    for (int j = 0; j < 4; ++j) {
                        const int row = m0 + mh * 128 + wm * 64 + mi * 16 + rbase + j;
                        float v = acc[mh][nh][mi][ni][j];
                        if (EPI && du)
                            v = fmaf(Dv[col], uu[(size_t)row * DMODEL + col], v);
                        if (OUTBF)
                            ((ushort_t*)Cv)[(size_t)row * ldc + col] = f2bf(v);
                        else
                            ((float*)Cv)[(size_t)row * ldc + col] = v;
                    }
                }
}

// ---------------------------------------------------------------------------
// fp32 -> bf16 (flat, 8 elements/thread)
// ---------------------------------------------------------------------------
__global__ __launch_bounds__(256) void conv_bf16(const float* __restrict__ s,
                                                 ushort_t* __restrict__ d, int n8) {
    const int i = blockIdx.x * 256 + threadIdx.x;
    if (i >= n8) return;
    const float4 a = reinterpret_cast<const float4*>(s)[2 * i];
    const float4 b = reinterpret_cast<const float4*>(s)[2 * i + 1];
    ushort_t o[8] = {f2bf(a.x), f2bf(a.y), f2bf(a.z), f2bf(a.w),
                     f2bf(b.x), f2bf(b.y), f2bf(b.z), f2bf(b.w)};
    reinterpret_cast<bf16x8*>(d)[i] = *reinterpret_cast<bf16x8*>(o);
}

// ---------------------------------------------------------------------------
// Chunked parallel scan, in place on bf16 UHb [bt][NSPEC].
// Re at col kf (0..512); Im at col 512+kf (kf=1..511). kf in {0,512}: real-only.
// ---------------------------------------------------------------------------
__global__ __launch_bounds__(256) void scan_local(ushort_t* __restrict__ UHb,
                                                  const float* __restrict__ lam) {
    const int gid = blockIdx.x * 256 + threadIdx.x;
    if (gid >= BATCH * NC * KFREQ) return;
    const int kf = gid % KFREQ;
    const int bc = gid / KFREQ;
    const int c = bc & (NC - 1);
    const int b = bc / NC;
    const bool him = (kf != 0 && kf != 512);
    const float lr = lam[kf];
    const float li = him ? lam[512 + kf] : 0.0f;
    ushort_t* base = UHb + ((size_t)(b * SEQLEN + c * TC)) * NSPEC + kf;
    float hr = 0.0f, hi = 0.0f;
    for (int t = 0; t < TC; ++t) {
        const float ur = bf2f(base[(size_t)t * NSPEC]);
        const float ui = him ? bf2f(base[(size_t)t * NSPEC + 512]) : 0.0f;
        const float nr = fmaf(lr, hr, fmaf(-li, hi, ur));
        const float ni = fmaf(lr, hi, fmaf(li, hr, ui));
        base[(size_t)t * NSPEC] = f2bf(nr);
        if (him) base[(size_t)t * NSPEC + 512] = f2bf(ni);
        hr = nr; hi = ni;
    }
}

__global__ __launch_bounds__(256) void scan_carry(const ushort_t* __restrict__ UHb,
                                                  const float* __restrict__ lam,
                                                  float* __restrict__ Ac) {
    const int gid = blockIdx.x * 256 + threadIdx.x;
    if (gid >= BATCH * KFREQ) return;
    const int kf = gid % KFREQ;
    const int b = gid / KFREQ;
    const bool him = (kf != 0 && kf != 512);
    const float lr = lam[kf];
    const float li = him ? lam[512 + kf] : 0.0f;
    float pr = lr, pi = li;          // lambda^64 via 6 squarings
    for (int s = 0; s < 6; ++s) {
        const float nr = pr * pr - pi * pi;
        const float ni = 2.0f * pr * pi;
        pr = nr; pi = ni;
    }
    float er = 0.0f, ei = 0.0f;
    for (int c = 0; c < NC; ++c) {
        const size_t ai = (size_t)(b * NC + c) * KFREQ + kf;
        Ac[ai] = er;
        Ac[(size_t)BATCH * NC * KFREQ + ai] = ei;
        const size_t gi = ((size_t)(b * SEQLEN + c * TC + TC - 1)) * NSPEC + kf;
        const float gr = bf2f(UHb[gi]);
        const float gm = him ? bf2f(UHb[gi + 512]) : 0.0f;
        const float nr = fmaf(pr, er, fmaf(-pi, ei, gr));
        const float ni = fmaf(pr, ei, fmaf(pi, er, gm));
        er = nr; ei = ni;
    }
}

__global__ __launch_bounds__(256) void scan_apply(ushort_t* __restrict__ UHb,
                                                  const float* __restrict__ lam,
                                                  const float* __restrict__ Ac) {
    const int gid = blockIdx.x * 256 + threadIdx.x;
    if (gid >= BATCH * NC * KFREQ) return;
    const int kf = gid % KFREQ;
    const int bc = gid / KFREQ;
    const int c = bc & (NC - 1);
    const int b = bc / NC;
    if (c == 0) return;                        // carry is zero
    const bool him = (kf != 0 && kf != 512);
    const float er = Ac[gid];
    const float ei = Ac[(size_t)BATCH * NC * KFREQ + gid];
    const float lr = lam[kf];
    const float li = him ? lam[512 + kf] : 0.0f;
    ushort_t* base = UHb + ((size_t)(b * SEQLEN + c * TC)) * NSPEC + kf;
    float pr = lr, pi = li;   // lambda^1
    for (int t = 0; t < TC; ++t) {
        const float hr = bf2f(base[(size_t)t * NSPEC]);
        const float hi = him ? bf2f(base[(size_t)t * NSPEC + 512]) : 0.0f;
        base[(size_t)t * NSPEC] = f2bf(fmaf(pr, er, fmaf(-pi, ei, hr)));
        if (him) base[(size_t)t * NSPEC + 512] = f2bf(fmaf(pr, ei, fmaf(pi, er, hi)));
        const float nr = fmaf(pr, lr, -pi * li);
        const float ni = fmaf(pr, li, pi * lr);
        pr = nr; pi = ni;
    }
}

// ---------------------------------------------------------------------------
extern "C" void kernel_launch(void* const* d_in, const int* in_sizes, int n_in,
                              void* d_out, int out_size, void* d_ws, size_t ws_size,
                              hipStream_t stream) {
    const float* u  = (const float*)d_in[0];  // [B][S][D]
    const float* ap = (const float*)d_in[1];  // [512]
    const float* Bw = (const float*)d_in[2];  // [N][D]
    const float* Cw = (const float*)d_in[3];  // [D][N]
    const float* Dv = (const float*)d_in[4];  // [D]
    float* out = (float*)d_out;               // [B][S][D]

    char* ws = (char*)d_ws;
    size_t off = 0;
    auto carve = [&](size_t bytes) { char* p = ws + off; off += (bytes + 255) & ~(size_t)255; return p; };

    ushort_t* UHb  = (ushort_t*)carve((size_t)BT_ROWS * NSPEC * sizeof(ushort_t));  // 33.6 MB
    ushort_t* ub   = (ushort_t*)carve((size_t)BT_ROWS * DMODEL * sizeof(ushort_t)); // 33.6 MB
    ushort_t* T1b  = (ushort_t*)carve((size_t)NSPEC * DMODEL * sizeof(ushort_t));
    ushort_t* T2b  = (ushort_t*)carve((size_t)NSPEC * DMODEL * sizeof(ushort_t));
    ushort_t* BwTb = (ushort_t*)carve((size_t)DMODEL * DMODEL * sizeof(ushort_t));
    ushort_t* Cwb  = (ushort_t*)carve((size_t)DMODEL * DMODEL * sizeof(ushort_t));
    ushort_t* W1b  = (ushort_t*)carve((size_t)NSPEC * DMODEL * sizeof(ushort_t));
    ushort_t* W2b  = (ushort_t*)carve((size_t)DMODEL * NSPEC * sizeof(ushort_t));
    float*    lam  = (float*)   carve(NSPEC * sizeof(float));
    int*      dflag= (int*)     carve(sizeof(int));
    float*    Ac   = (float*)   carve((size_t)2 * BATCH * NC * KFREQ * sizeof(float));

    // 1) eigenvalues + D flag
    compute_lambda<<<1, 1024, 0, stream>>>(ap, lam, Dv, dflag);

    // 2) trig matrices (bf16) + operand conversions
    gen_Tb<<<NSPEC * DMODEL / 8 / 256, 256, 0, stream>>>(T1b, 0);
    gen_Tb<<<NSPEC * DMODEL / 8 / 256, 256, 0, stream>>>(T2b, 1);
    {
        dim3 g(DMODEL / 64, DMODEL / 64);
        transp_conv<<<g, 256, 0, stream>>>(Bw, BwTb);
    }
    conv_bf16<<<DMODEL * DMODEL / 8 / 256, 256, 0, stream>>>(Cw, Cwb, DMODEL * DMODEL / 8);
    conv_bf16<<<BT_ROWS * (DMODEL / 8) / 256, 256, 0, stream>>>(u, ub, BT_ROWS * (DMODEL / 8));

    // 3) W1b[spec][d] = T1b @ BwTb^T
    {
        dim3 g(NSPEC / 128, DMODEL / 128);
        gemm128<<<g, 256, 0, stream>>>(T1b, BwTb, W1b, NSPEC, DMODEL, DMODEL);
    }
    // 4) W2b[d][spec] = Cwb @ T2b^T
    {
        dim3 g(DMODEL / 128, NSPEC / 128);
        gemm128<<<g, 256, 0, stream>>>(Cwb, T2b, W2b, DMODEL, NSPEC, DMODEL);
    }

    // 5) UHb[bt][spec] = ub @ W1b^T   (256^2 8-phase, bf16 out)
    {
        dim3 g(BT_ROWS / 256, NSPEC / 256);
        gemm256<false, true><<<g, 512, 0, stream>>>(ub, W1b, UHb,
            BT_ROWS, DMODEL, NSPEC, nullptr, nullptr, dflag);
    }

    // 6) scan over time (in place on bf16): local, carry, apply
    scan_local<<<(BATCH * NC * KFREQ + 255) / 256, 256, 0, stream>>>(UHb, lam);
    scan_carry<<<(BATCH * KFREQ + 255) / 256, 256, 0, stream>>>(UHb, lam, Ac);
    scan_apply<<<(BATCH * NC * KFREQ + 255) / 256, 256, 0, stream>>>(UHb, lam, Ac);

    // 7) y = UHb @ W2b^T + D*u   (256^2 8-phase, fp32 out)
    {
        dim3 g(BT_ROWS / 256, DMODEL / 256);
        gemm256<true, false><<<g, 512, 0, stream>>>(UHb, W2b, out,
            BT_ROWS, NSPEC, DMODEL, u, Dv, dflag);
    }
}

// Round 9
// 159.075 us; speedup vs baseline: 1.8638x; 1.4793x over previous
//
#include <hip/hip_runtime.h>
#include <math.h>

// Problem constants
#define BATCH   8
#define SEQLEN  2048
#define DMODEL  1024
#define KFREQ   513        // unique half-spectrum freqs 0..512
#define NSPEC   1024       // pair layout: col 2j=Re_j, col 2j+1=Im_j (j=1..511); col1 = Re_512
#define NPAIR   512
#define BT_ROWS (BATCH*SEQLEN)   // 16384
#define NC      32         // time chunks for parallel scan
#define TC      64         // chunk length; NC*TC == SEQLEN

static_assert(NC * TC == SEQLEN, "chunking must cover SEQLEN");

typedef __attribute__((ext_vector_type(4))) float f32x4;
typedef __attribute__((ext_vector_type(8))) short bf16x8;   // 8 bf16 in 4 VGPRs
typedef unsigned short ushort_t;
typedef unsigned int uint_t;

__device__ __forceinline__ ushort_t f2bf(float f) {
    union { float f; unsigned u; } v; v.f = f;
    unsigned r = v.u + 0x7FFFu + ((v.u >> 16) & 1u);   // RNE
    return (ushort_t)(r >> 16);
}
__device__ __forceinline__ float bf2f(ushort_t b) {
    union { unsigned u; float f; } v; v.u = ((unsigned)b) << 16;
    return v.f;
}

__device__ __forceinline__ void async_cp16(const void* g, void* l) {
    __builtin_amdgcn_global_load_lds(
        (const __attribute__((address_space(1))) void*)g,
        (__attribute__((address_space(3))) void*)l, 16, 0, 0);
}

#define BAR()   __builtin_amdgcn_s_barrier()
#define PRIO1() __builtin_amdgcn_s_setprio(1)
#define PRIO0() __builtin_amdgcn_s_setprio(0)
#define LGKM0() asm volatile("s_waitcnt lgkmcnt(0)" ::: "memory")
#define LGKM8() asm volatile("s_waitcnt lgkmcnt(8)" ::: "memory")
#define VM6()   asm volatile("s_waitcnt vmcnt(6)" ::: "memory")
#define VM0()   asm volatile("s_waitcnt vmcnt(0)" ::: "memory")

// ---------------------------------------------------------------------------
// lambda_k = (1 - i w)/(1 + i w),  w = Im(FFT(a_full))[k]
// Pair layout: lam[2j]=Re(λ_j) j=0..511; lam[2j+1]=Im(λ_j) j=1..511;
// lam[1]=Re(λ_512) (Nyquist, Im≡0; DC Im≡0 too).
// Also dflag = any(D != 0).
// ---------------------------------------------------------------------------
__global__ __launch_bounds__(1024) void compute_lambda(const float* __restrict__ p,
                                                       float* __restrict__ lam,
                                                       const float* __restrict__ Dv,
                                                       int* __restrict__ dflag) {
    __shared__ float stab[1024];
    __shared__ int anyd;
    const int tid = threadIdx.x;
    if (tid == 0) anyd = 0;
    stab[tid] = sinf((float)tid * (6.28318530717958647692f / 1024.0f));
    __syncthreads();
    if (Dv[tid] != 0.0f) anyd = 1;     // benign race, same value
    if (tid < KFREQ) {
        float om = 0.0f;
        for (int j = 1; j <= 511; ++j)
            om = fmaf(p[j - 1], stab[(j * tid) & 1023], om);
        om *= -2.0f;
        const float w2 = om * om;
        const float den = 1.0f + w2;
        const float re = (1.0f - w2) / den;
        const float im = -2.0f * om / den;
        if (tid == 0)        lam[0] = re;
        else if (tid == 512) lam[1] = re;
        else { lam[2 * tid] = re; lam[2 * tid + 1] = im; }
    }
    __syncthreads();
    if (tid == 0) *dflag = anyd;
}

// ---------------------------------------------------------------------------
// Trig matrices (both modes in one launch, blockIdx.y = mode), bf16 [NSPEC][DMODEL].
// Pair-layout rows: r=2j -> cos(2π j n/1024); r=2j+1 (j>=1) -> -sin(2π j n/1024);
// r=1 -> cos(π n) (Nyquist Re basis).
// mode 0: scale 1. mode 1: scale = ((r<2)?1:2)/1024.
// ---------------------------------------------------------------------------
__global__ __launch_bounds__(256) void gen_Tb2(ushort_t* __restrict__ T0,
                                               ushort_t* __restrict__ T1) {
    __shared__ float stab[1024];
    for (int j = threadIdx.x; j < 1024; j += 256)
        stab[j] = sinf((float)j * (6.28318530717958647692f / 1024.0f));
    __syncthreads();

    const int mode = blockIdx.y;
    ushort_t* T = mode ? T1 : T0;
    const int i = blockIdx.x * 256 + threadIdx.x;   // 8 elements per thread
    const int row = i >> 7;
    const int nb  = (i & 127) << 3;

    const int kf  = (row == 1) ? 512 : (row >> 1);
    const bool sb = (row & 1) && (row != 1);        // sine basis?
    float scale = 1.0f;
    if (mode == 1) scale = ((row < 2) ? 1.0f : 2.0f) / 1024.0f;

    ushort_t o[8];
    int m = (kf * nb) & 1023;
#pragma unroll
    for (int j = 0; j < 8; ++j) {
        const float v = sb ? -stab[m] : stab[(m + 256) & 1023];
        o[j] = f2bf(v * scale);
        m = (m + kf) & 1023;
    }
    reinterpret_cast<bf16x8*>(T)[i] = *reinterpret_cast<bf16x8*>(o);
}

// ---------------------------------------------------------------------------
// Transpose-convert: dst[c][r] (bf16, 1024x1024) = src[r][c] (fp32)
// ---------------------------------------------------------------------------
__global__ __launch_bounds__(256) void transp_conv(const float* __restrict__ s,
                                                   ushort_t* __restrict__ d) {
    __shared__ float tile[64][65];
    const int bx = blockIdx.x * 64;
    const int by = blockIdx.y * 64;
    const int lx = threadIdx.x & 63;
    const int ly = threadIdx.x >> 6;
#pragma unroll
    for (int i = 0; i < 16; ++i) {
        const int r = ly + i * 4;
        tile[r][lx] = s[(size_t)(by + r) * DMODEL + bx + lx];
    }
    __syncthreads();
#pragma unroll
    for (int i = 0; i < 16; ++i) {
        const int r = ly + i * 4;
        d[(size_t)(bx + r) * DMODEL + by + lx] = f2bf(tile[lx][r]);
    }
}

// ---------------------------------------------------------------------------
// Fused fp32->bf16 conversion for u (8192 blocks) and Cw (512 blocks).
// ---------------------------------------------------------------------------
#define NU8 (BT_ROWS * DMODEL / 8 / 256)     // 8192
#define NW8 (DMODEL * DMODEL / 8 / 256)      // 512
__global__ __launch_bounds__(256) void conv_fuse(const float* __restrict__ u,
                                                 ushort_t* __restrict__ ub,
                                                 const float* __restrict__ Cw,
                                                 ushort_t* __restrict__ Cwb) {
    const float* s; ushort_t* d; int i;
    if (blockIdx.x < NU8) { s = u;  d = ub;  i = blockIdx.x * 256 + threadIdx.x; }
    else                  { s = Cw; d = Cwb; i = (blockIdx.x - NU8) * 256 + threadIdx.x; }
    const float4 a = reinterpret_cast<const float4*>(s)[2 * i];
    const float4 b = reinterpret_cast<const float4*>(s)[2 * i + 1];
    ushort_t o[8] = {f2bf(a.x), f2bf(a.y), f2bf(a.z), f2bf(a.w),
                     f2bf(b.x), f2bf(b.y), f2bf(b.z), f2bf(b.w)};
    reinterpret_cast<bf16x8*>(d)[i] = *reinterpret_cast<bf16x8*>(o);
}

// ---------------------------------------------------------------------------
// 128x128 BK=32 bf16 MFMA GEMM — both weight-precompute GEMMs in one dispatch
// (blockIdx.z selects operand triple). C (bf16) [1024][1024] = A @ B^T.
// ---------------------------------------------------------------------------
__global__ __launch_bounds__(256) void gemm128z(const ushort_t* __restrict__ A0,
                                                const ushort_t* __restrict__ B0,
                                                ushort_t* __restrict__ C0,
                                                const ushort_t* __restrict__ A1,
                                                const ushort_t* __restrict__ B1,
                                                ushort_t* __restrict__ C1) {
    const int K = 1024, N = 1024;
    const ushort_t* A = blockIdx.z ? A1 : A0;
    const ushort_t* B = blockIdx.z ? B1 : B0;
    ushort_t*       C = blockIdx.z ? C1 : C0;
    __shared__ ushort_t As[128 * 32];
    __shared__ ushort_t Bs[128 * 32];
    const int tid  = threadIdx.x;
    const int lane = tid & 63;
    const int w    = tid >> 6;
    const int m0 = blockIdx.x * 128;
    const int n0 = blockIdx.y * 128;
    const int wr = (w >> 1) * 64;
    const int wc = (w & 1) * 64;

    f32x4 acc[4][4] = {};

    const int pos  = w * 512 + lane * 8;
    const int srow = pos >> 5;
    const int scol = pos & 31;
    const int lr = lane & 15;
    const int lk = (lane >> 4) * 8;

    for (int k0 = 0; k0 < K; k0 += 32) {
        __syncthreads();
        async_cp16(A + (size_t)(m0 + srow)      * K + k0 + scol, As + w * 512);
        async_cp16(A + (size_t)(m0 + srow + 64) * K + k0 + scol, As + 2048 + w * 512);
        async_cp16(B + (size_t)(n0 + srow)      * K + k0 + scol, Bs + w * 512);
        async_cp16(B + (size_t)(n0 + srow + 64) * K + k0 + scol, Bs + 2048 + w * 512);
        __syncthreads();

        bf16x8 fa[4], fb[4];
#pragma unroll
        for (int mi = 0; mi < 4; ++mi)
            fa[mi] = *reinterpret_cast<const bf16x8*>(&As[(wr + mi * 16 + lr) * 32 + lk]);
#pragma unroll
        for (int ni = 0; ni < 4; ++ni)
            fb[ni] = *reinterpret_cast<const bf16x8*>(&Bs[(wc + ni * 16 + lr) * 32 + lk]);
#pragma unroll
        for (int mi = 0; mi < 4; ++mi)
#pragma unroll
            for (int ni = 0; ni < 4; ++ni)
                acc[mi][ni] = __builtin_amdgcn_mfma_f32_16x16x32_bf16(
                    fa[mi], fb[ni], acc[mi][ni], 0, 0, 0);
    }

    const int rbase = (lane >> 4) * 4;
#pragma unroll
    for (int mi = 0; mi < 4; ++mi)
#pragma unroll
        for (int ni = 0; ni < 4; ++ni) {
            const int col = n0 + wc + ni * 16 + lr;
#pragma unroll
            for (int j = 0; j < 4; ++j) {
                const int row = m0 + wr + mi * 16 + rbase + j;
                C[(size_t)row * N + col] = f2bf(acc[mi][ni][j]);
            }
        }
}

// ---------------------------------------------------------------------------
// 256x256 8-wave bf16 MFMA GEMM — m201-style 8-phase schedule (round-8 proven).
// ---------------------------------------------------------------------------
template <int MH, int NH>
__device__ __forceinline__ void quad_mfma(f32x4 (&acc)[2][2][4][2],
                                          const bf16x8 (&fa)[4][2],
                                          const bf16x8 (&fb)[2][2]) {
#pragma unroll
    for (int mi = 0; mi < 4; ++mi)
#pragma unroll
        for (int ni = 0; ni < 2; ++ni) {
            acc[MH][NH][mi][ni] = __builtin_amdgcn_mfma_f32_16x16x32_bf16(
                fa[mi][0], fb[ni][0], acc[MH][NH][mi][ni], 0, 0, 0);
            acc[MH][NH][mi][ni] = __builtin_amdgcn_mfma_f32_16x16x32_bf16(
                fa[mi][1], fb[ni][1], acc[MH][NH][mi][ni], 0, 0, 0);
        }
}

__device__ __forceinline__ void ld_fa(bf16x8 (&fa)[4][2], const ushort_t* hb,
                                      int wm, int lr, int c0, int c1) {
#pragma unroll
    for (int mi = 0; mi < 4; ++mi) {
        const ushort_t* p = hb + (wm * 64 + mi * 16 + lr) * 64;
        fa[mi][0] = *reinterpret_cast<const bf16x8*>(p + c0);
        fa[mi][1] = *reinterpret_cast<const bf16x8*>(p + c1);
    }
}
__device__ __forceinline__ void ld_fb(bf16x8 (&fb)[2][2], const ushort_t* hb,
                                      int wn, int lr, int c0, int c1) {
#pragma unroll
    for (int ni = 0; ni < 2; ++ni) {
        const ushort_t* p = hb + (wn * 32 + ni * 16 + lr) * 64;
        fb[ni][0] = *reinterpret_cast<const bf16x8*>(p + c0);
        fb[ni][1] = *reinterpret_cast<const bf16x8*>(p + c1);
    }
}

template <bool EPI, bool OUTBF>
__global__ __launch_bounds__(512, 2) void gemm256(const ushort_t* __restrict__ A,
                                                  const ushort_t* __restrict__ B,
                                                  void* __restrict__ Cv,
                                                  int M, int K, int ldc,
                                                  const float* __restrict__ uu,
                                                  const float* __restrict__ Dv,
                                                  const int* __restrict__ dflag) {
    __shared__ ushort_t As[2][2][128][64];   // [buf][half][row][col] 64 KB
    __shared__ ushort_t Bs[2][2][128][64];
    const int tid  = threadIdx.x;
    const int lane = tid & 63;
    const int w    = tid >> 6;      // 0..7
    const int wm   = w >> 2;        // 0..1
    const int wn   = w & 3;         // 0..3
    const int m0 = blockIdx.x * 256;
    const int n0 = blockIdx.y * 256;
    const int lr = lane & 15;
    const int lk = (lane >> 4) * 8;
    const int xv = (lr & 7) << 3;
    const int c0 = lk ^ xv;
    const int c1 = (32 + lk) ^ xv;

    const int rA = tid >> 3;                             // staging row 0..63
    const int cS = ((tid & 7) << 3) ^ ((rA & 7) << 3);   // pre-swizzled src col
    const int ldsOff = w << 9;                           // wave-uniform elems

    f32x4 acc[2][2][4][2] = {};
    bf16x8 fa[4][2], fbl[2][2], fbh[2][2];

    auto stA = [&](int buf, int half, int k) {
#pragma unroll
        for (int li = 0; li < 2; ++li)
            async_cp16(A + (size_t)(m0 + half * 128 + li * 64 + rA) * K + k + cS,
                       &As[buf][half][0][0] + li * 4096 + ldsOff);
    };
    auto stB = [&](int buf, int half, int k) {
#pragma unroll
        for (int li = 0; li < 2; ++li)
            async_cp16(B + (size_t)(n0 + half * 128 + li * 64 + rA) * K + k + cS,
                       &Bs[buf][half][0][0] + li * 4096 + ldsOff);
    };

    // prologue: tile0 fully, tile1 minus A-hi (staged at P1 of iter 0)
    stA(0, 0, 0); stB(0, 0, 0); stB(0, 1, 0); stA(0, 1, 0);
    stA(1, 0, 64); stB(1, 0, 64); stB(1, 1, 64);
    VM6();            // oldest 8 loads (= all of tile0) landed
    BAR();

    const int niter = K >> 7;       // 2 tiles per iteration
#pragma unroll 1
    for (int t = 0; t < niter - 1; ++t) {
        const int kb1 = (t << 7) + 64;      // tile 2t+1
        const int kn  = (t + 1) << 7;       // tile 2t+2
        const int kn2 = kn + 64;            // tile 2t+3
        // P1: quad (0,0) of tile 2t
        ld_fa(fa, &As[0][0][0][0], wm, lr, c0, c1);
        ld_fb(fbl, &Bs[0][0][0][0], wn, lr, c0, c1);
        stA(1, 1, kb1);
        LGKM8();
        BAR(); LGKM0();
        PRIO1(); quad_mfma<0, 0>(acc, fa, fbl); PRIO0();
        BAR();
        // P2: quad (0,1)
        ld_fb(fbh, &Bs[0][1][0][0], wn, lr, c0, c1);
        stA(0, 0, kn);
        BAR(); LGKM0();
        PRIO1(); quad_mfma<0, 1>(acc, fa, fbh); PRIO0();
        BAR();
        // P3: quad (1,1)
        ld_fa(fa, &As[0][1][0][0], wm, lr, c0, c1);
        stB(0, 0, kn);
        BAR(); LGKM0();
        PRIO1(); quad_mfma<1, 1>(acc, fa, fbh); PRIO0();
        BAR();
        // P4: quad (1,0)  — no reads; counted vmcnt
        stB(0, 1, kn);
        VM6();
        BAR();
        PRIO1(); quad_mfma<1, 0>(acc, fa, fbl); PRIO0();
        BAR();
        // P5: quad (0,0) of tile 2t+1
        ld_fa(fa, &As[1][0][0][0], wm, lr, c0, c1);
        ld_fb(fbl, &Bs[1][0][0][0], wn, lr, c0, c1);
        stA(0, 1, kn);
        LGKM8();
        BAR(); LGKM0();
        PRIO1(); quad_mfma<0, 0>(acc, fa, fbl); PRIO0();
        BAR();
        // P6: quad (0,1)
        ld_fb(fbh, &Bs[1][1][0][0], wn, lr, c0, c1);
        stA(1, 0, kn2);
        BAR(); LGKM0();
        PRIO1(); quad_mfma<0, 1>(acc, fa, fbh); PRIO0();
        BAR();
        // P7: quad (1,1)
        ld_fa(fa, &As[1][1][0][0], wm, lr, c0, c1);
        stB(1, 0, kn2);
        BAR(); LGKM0();
        PRIO1(); quad_mfma<1, 1>(acc, fa, fbh); PRIO0();
        BAR();
        // P8: quad (1,0)
        stB(1, 1, kn2);
        VM6();
        BAR();
        PRIO1(); quad_mfma<1, 0>(acc, fa, fbl); PRIO0();
        BAR();
    }
    // ---- epilogue iteration: only P1 stages ----
    {
        const int kb1 = ((niter - 1) << 7) + 64;
        // P1
        ld_fa(fa, &As[0][0][0][0], wm, lr, c0, c1);
        ld_fb(fbl, &Bs[0][0][0][0], wn, lr, c0, c1);
        stA(1, 1, kb1);
        LGKM8();
        BAR(); LGKM0();
        PRIO1(); quad_mfma<0, 0>(acc, fa, fbl); PRIO0();
        BAR();
        // P2
        ld_fb(fbh, &Bs[0][1][0][0], wn, lr, c0, c1);
        BAR(); LGKM0();
        PRIO1(); quad_mfma<0, 1>(acc, fa, fbh); PRIO0();
        BAR();
        // P3
        ld_fa(fa, &As[0][1][0][0], wm, lr, c0, c1);
        BAR(); LGKM0();
        PRIO1(); quad_mfma<1, 1>(acc, fa, fbh); PRIO0();
        BAR();
        // P4: drain everything
        VM0();
        BAR();
        PRIO1(); quad_mfma<1, 0>(acc, fa, fbl); PRIO0();
        BAR();
        // P5
        ld_fa(fa, &As[1][0][0][0], wm, lr, c0, c1);
        ld_fb(fbl, &Bs[1][0][0][0], wn, lr, c0, c1);
        BAR(); LGKM0();
        PRIO1(); quad_mfma<0, 0>(acc, fa, fbl); PRIO0();
        BAR();
        // P6
        ld_fb(fbh, &Bs[1][1][0][0], wn, lr, c0, c1);
        BAR(); LGKM0();
        PRIO1(); quad_mfma<0, 1>(acc, fa, fbh); PRIO0();
        BAR();
        // P7
        ld_fa(fa, &As[1][1][0][0], wm, lr, c0, c1);
        BAR(); LGKM0();
        PRIO1(); quad_mfma<1, 1>(acc, fa, fbh); PRIO0();
        BAR();
        // P8
        PRIO1(); quad_mfma<1, 0>(acc, fa, fbl); PRIO0();
    }

    // C write
    const int rbase = (lane >> 4) * 4;
    const bool du = EPI && (*dflag != 0);
#pragma unroll
    for (int mh = 0; mh < 2; ++mh)
#pragma unroll
        for (int nh = 0; nh < 2; ++nh)
#pragma unroll
            for (int mi = 0; mi < 4; ++mi)
#pragma unroll
                for (int ni = 0; ni < 2; ++ni) {
                    const int col = n0 + nh * 128 + wn * 32 + ni * 16 + lr;
#pragma unroll
                    for (int j = 0; j < 4; ++j) {
                        const int row = m0 + mh * 128 + wm * 64 + mi * 16 + rbase + j;
                        float v = acc[mh][nh][mi][ni][j];
                        if (EPI && du)
                            v = fmaf(Dv[col], uu[(size_t)row * DMODEL + col], v);
                        if (OUTBF)
                            ((ushort_t*)Cv)[(size_t)row * ldc + col] = f2bf(v);
                        else
                            ((float*)Cv)[(size_t)row * ldc + col] = v;
                    }
                }
}

// ---------------------------------------------------------------------------
// Scan (pair layout). Generalized per-pair recurrence:
//   [hr,hi] <- [lr*hr - cross*hi + ur,  lr2*hi + cross*hr + ui]
// j>=1: lr2=lr, cross=Im λ_j (complex).  j=0: cross=0, lr=λ_0, lr2=λ_512
// (two independent real recurrences: DC in .x, Nyquist in .y).
// ---------------------------------------------------------------------------
__device__ __forceinline__ void pair_coef(const float* lam, int j,
                                          float& lr, float& lr2, float& cr) {
    const float a = lam[2 * j];
    const float b = lam[2 * j + 1];
    if (j == 0) { lr = a; lr2 = b; cr = 0.0f; }
    else        { lr = a; lr2 = a; cr = b; }
}

// pass G: chunk-end states (read U, write G)
__global__ __launch_bounds__(256) void scan_ends(const ushort_t* __restrict__ UHb,
                                                 const float* __restrict__ lam,
                                                 float2* __restrict__ G) {
    const int gid = blockIdx.x * 256 + threadIdx.x;   // BATCH*NC*NPAIR
    const int j = gid & (NPAIR - 1);
    const int c = (gid >> 9) & (NC - 1);
    const int b = gid >> 14;
    float lr, lr2, cr;
    pair_coef(lam, j, lr, lr2, cr);
    const uint_t* base = reinterpret_cast<const uint_t*>(
        UHb + (size_t)(b * SEQLEN + c * TC) * NSPEC) + j;
    float er = 0.0f, ei = 0.0f;
    for (int t = 0; t < TC; ++t) {
        const uint_t v = base[(size_t)t * NPAIR];
        const float ur = bf2f((ushort_t)(v & 0xFFFF));
        const float ui = bf2f((ushort_t)(v >> 16));
        const float nr = fmaf(lr, er, fmaf(-cr, ei, ur));
        const float ni = fmaf(lr2, ei, fmaf(cr, er, ui));
        er = nr; ei = ni;
    }
    G[gid] = make_float2(er, ei);
}

// carry: E_c = carry INTO chunk c (state at end of chunk c-1), via Λ^64
__global__ __launch_bounds__(256) void scan_carry(const float2* __restrict__ G,
                                                  const float* __restrict__ lam,
                                                  float2* __restrict__ Ac) {
    const int gid = blockIdx.x * 256 + threadIdx.x;   // BATCH*NPAIR
    if (gid >= BATCH * NPAIR) return;
    const int j = gid & (NPAIR - 1);
    const int b = gid >> 9;
    float lr, lr2, cr;
    pair_coef(lam, j, lr, lr2, cr);
    // Λ^64 via 6 squarings in the closed (lr, lr2, cross) form
    float pr = lr, pr2 = lr2, pc = cr;
    for (int s = 0; s < 6; ++s) {
        const float nr  = pr * pr - pc * pc;
        const float nr2 = pr2 * pr2 - pc * pc;
        const float npc = pc * (pr + pr2);
        pr = nr; pr2 = nr2; pc = npc;
    }
    float er = 0.0f, ei = 0.0f;
    for (int c = 0; c < NC; ++c) {
        const int idx = (b * NC + c) * NPAIR + j;
        Ac[idx] = make_float2(er, ei);
        const float2 g = G[idx];
        const float nr = fmaf(pr, er, fmaf(-pc, ei, g.x));
        const float ni = fmaf(pr2, ei, fmaf(pc, er, g.y));
        er = nr; ei = ni;
    }
}

// pass F: full scan seeded with carry; single bf16 rounding of H (in place)
__global__ __launch_bounds__(256) void scan_final(ushort_t* __restrict__ UHb,
                                                  const float* __restrict__ lam,
                                                  const float2* __restrict__ Ac) {
    const int gid = blockIdx.x * 256 + threadIdx.x;   // BATCH*NC*NPAIR
    const int j = gid & (NPAIR - 1);
    const int c = (gid >> 9) & (NC - 1);
    const int b = gid >> 14;
    float lr, lr2, cr;
    pair_coef(lam, j, lr, lr2, cr);
    const float2 e0 = Ac[(b * NC + c) * NPAIR + j];
    float er = e0.x, ei = e0.y;
    uint_t* base = reinterpret_cast<uint_t*>(
        UHb + (size_t)(b * SEQLEN + c * TC) * NSPEC) + j;
    for (int t = 0; t < TC; ++t) {
        const uint_t v = base[(size_t)t * NPAIR];
        const float ur = bf2f((ushort_t)(v & 0xFFFF));
        const float ui = bf2f((ushort_t)(v >> 16));
        const float nr = fmaf(lr, er, fmaf(-cr, ei, ur));
        const float ni = fmaf(lr2, ei, fmaf(cr, er, ui));
        base[(size_t)t * NPAIR] = (uint_t)f2bf(nr) | ((uint_t)f2bf(ni) << 16);
        er = nr; ei = ni;
    }
}

// ---------------------------------------------------------------------------
extern "C" void kernel_launch(void* const* d_in, const int* in_sizes, int n_in,
                              void* d_out, int out_size, void* d_ws, size_t ws_size,
                              hipStream_t stream) {
    const float* u  = (const float*)d_in[0];  // [B][S][D]
    const float* ap = (const float*)d_in[1];  // [512]
    const float* Bw = (const float*)d_in[2];  // [N][D]
    const float* Cw = (const float*)d_in[3];  // [D][N]
    const float* Dv = (const float*)d_in[4];  // [D]
    float* out = (float*)d_out;               // [B][S][D]

    char* ws = (char*)d_ws;
    size_t off = 0;
    auto carve = [&](size_t bytes) { char* p = ws + off; off += (bytes + 255) & ~(size_t)255; return p; };

    ushort_t* UHb  = (ushort_t*)carve((size_t)BT_ROWS * NSPEC * sizeof(ushort_t));  // 33.6 MB
    ushort_t* ub   = (ushort_t*)carve((size_t)BT_ROWS * DMODEL * sizeof(ushort_t)); // 33.6 MB
    ushort_t* T1b  = (ushort_t*)carve((size_t)NSPEC * DMODEL * sizeof(ushort_t));
    ushort_t* T2b  = (ushort_t*)carve((size_t)NSPEC * DMODEL * sizeof(ushort_t));
    ushort_t* BwTb = (ushort_t*)carve((size_t)DMODEL * DMODEL * sizeof(ushort_t));
    ushort_t* Cwb  = (ushort_t*)carve((size_t)DMODEL * DMODEL * sizeof(ushort_t));
    ushort_t* W1b  = (ushort_t*)carve((size_t)NSPEC * DMODEL * sizeof(ushort_t));
    ushort_t* W2b  = (ushort_t*)carve((size_t)DMODEL * NSPEC * sizeof(ushort_t));
    float*    lam  = (float*)   carve(NSPEC * sizeof(float));
    int*      dflag= (int*)     carve(sizeof(int));
    float2*   G    = (float2*)  carve((size_t)BATCH * NC * NPAIR * sizeof(float2));
    float2*   Ac   = (float2*)  carve((size_t)BATCH * NC * NPAIR * sizeof(float2));

    // 1) eigenvalues + D flag
    compute_lambda<<<1, 1024, 0, stream>>>(ap, lam, Dv, dflag);

    // 2) trig matrices (one dispatch, y=mode) + transposed Bw + fused conversions
    {
        dim3 g(NSPEC * DMODEL / 8 / 256, 2);
        gen_Tb2<<<g, 256, 0, stream>>>(T1b, T2b);
    }
    {
        dim3 g(DMODEL / 64, DMODEL / 64);
        transp_conv<<<g, 256, 0, stream>>>(Bw, BwTb);
    }
    conv_fuse<<<NU8 + NW8, 256, 0, stream>>>(u, ub, Cw, Cwb);

    // 3+4) both precompute GEMMs in one dispatch:
    //      z=0: W1b = T1b @ BwTb^T ;  z=1: W2b = Cwb @ T2b^T
    {
        dim3 g(8, 8, 2);
        gemm128z<<<g, 256, 0, stream>>>(T1b, BwTb, W1b, Cwb, T2b, W2b);
    }

    // 5) UHb[bt][spec] = ub @ W1b^T   (256^2 8-phase, bf16 out)
    {
        dim3 g(BT_ROWS / 256, NSPEC / 256);
        gemm256<false, true><<<g, 512, 0, stream>>>(ub, W1b, UHb,
            BT_ROWS, DMODEL, NSPEC, nullptr, nullptr, dflag);
    }

    // 6) scan: chunk-ends -> carries -> final (in place on UHb)
    scan_ends <<<BATCH * NC * NPAIR / 256, 256, 0, stream>>>(UHb, lam, G);
    scan_carry<<<(BATCH * NPAIR + 255) / 256, 256, 0, stream>>>(G, lam, Ac);
    scan_final<<<BATCH * NC * NPAIR / 256, 256, 0, stream>>>(UHb, lam, Ac);

    // 7) y = UHb @ W2b^T + D*u   (256^2 8-phase, fp32 out)
    {
        dim3 g(BT_ROWS / 256, DMODEL / 256);
        gemm256<true, false><<<g, 512, 0, stream>>>(UHb, W2b, out,
            BT_ROWS, NSPEC, DMODEL, u, Dv, dflag);
    }
}

// Round 10
// 149.028 us; speedup vs baseline: 1.9894x; 1.0674x over previous
//
#include <hip/hip_runtime.h>
#include <math.h>

// Problem constants
#define BATCH   8
#define SEQLEN  2048
#define DMODEL  1024
#define KFREQ   513
#define NSPEC   1024       // pair layout: col 2j=Re_j, col 2j+1=Im_j (j=1..511); col1 = Re_512
#define NPAIR   512
#define BT_ROWS (BATCH*SEQLEN)   // 16384
#define NC      32
#define TC      64

static_assert(NC * TC == SEQLEN, "chunking must cover SEQLEN");

typedef __attribute__((ext_vector_type(4))) float f32x4;
typedef __attribute__((ext_vector_type(8))) short bf16x8;
typedef unsigned short ushort_t;
typedef unsigned int uint_t;

__device__ __forceinline__ ushort_t f2bf(float f) {
    union { float f; unsigned u; } v; v.f = f;
    unsigned r = v.u + 0x7FFFu + ((v.u >> 16) & 1u);   // RNE
    return (ushort_t)(r >> 16);
}
__device__ __forceinline__ float bf2f(ushort_t b) {
    union { unsigned u; float f; } v; v.u = ((unsigned)b) << 16;
    return v.f;
}

__device__ __forceinline__ void async_cp16(const void* g, void* l) {
    __builtin_amdgcn_global_load_lds(
        (const __attribute__((address_space(1))) void*)g,
        (__attribute__((address_space(3))) void*)l, 16, 0, 0);
}

#define BAR()   __builtin_amdgcn_s_barrier()
#define PRIO1() __builtin_amdgcn_s_setprio(1)
#define PRIO0() __builtin_amdgcn_s_setprio(0)
#define LGKM0() asm volatile("s_waitcnt lgkmcnt(0)" ::: "memory")
#define LGKM8() asm volatile("s_waitcnt lgkmcnt(8)" ::: "memory")
#define VM6()   asm volatile("s_waitcnt vmcnt(6)" ::: "memory")
#define VM0()   asm volatile("s_waitcnt vmcnt(0)" ::: "memory")

// ---------------------------------------------------------------------------
// lambda: pair layout lam[2j]=Re λ_j (j=0..511), lam[2j+1]=Im λ_j (j=1..511),
// lam[1]=Re λ_512.  dflag = any(D != 0).
// ---------------------------------------------------------------------------
__global__ __launch_bounds__(1024) void compute_lambda(const float* __restrict__ p,
                                                       float* __restrict__ lam,
                                                       const float* __restrict__ Dv,
                                                       int* __restrict__ dflag) {
    __shared__ float stab[1024];
    __shared__ int anyd;
    const int tid = threadIdx.x;
    if (tid == 0) anyd = 0;
    stab[tid] = sinf((float)tid * (6.28318530717958647692f / 1024.0f));
    __syncthreads();
    if (Dv[tid] != 0.0f) anyd = 1;     // benign race, same value
    if (tid < KFREQ) {
        float om = 0.0f;
        for (int j = 1; j <= 511; ++j)
            om = fmaf(p[j - 1], stab[(j * tid) & 1023], om);
        om *= -2.0f;
        const float w2 = om * om;
        const float den = 1.0f + w2;
        const float re = (1.0f - w2) / den;
        const float im = -2.0f * om / den;
        if (tid == 0)        lam[0] = re;
        else if (tid == 512) lam[1] = re;
        else { lam[2 * tid] = re; lam[2 * tid + 1] = im; }
    }
    __syncthreads();
    if (tid == 0) *dflag = anyd;
}

// ---------------------------------------------------------------------------
// prep_all: one dispatch for (a) both trig matrices, (b) Bw transpose-convert,
// (c) u -> bf16, (d) Cw -> bf16.  Block ranges select the job.
// ---------------------------------------------------------------------------
#define NB_T  (NSPEC * DMODEL / 8 / 256)     // 512 per mode
#define NB_TR 256                            // 16x16 transpose blocks
#define NB_U  (BT_ROWS * DMODEL / 8 / 256)   // 8192
#define NB_CW (DMODEL * DMODEL / 8 / 256)    // 512

__global__ __launch_bounds__(256) void prep_all(const float* __restrict__ u,
                                                ushort_t* __restrict__ ub,
                                                const float* __restrict__ Cw,
                                                ushort_t* __restrict__ Cwb,
                                                const float* __restrict__ Bw,
                                                ushort_t* __restrict__ BwTb,
                                                ushort_t* __restrict__ T1b,
                                                ushort_t* __restrict__ T2b) {
    const int bid = blockIdx.x;
    if (bid < 2 * NB_T) {
        // --- trig matrix, pair-layout rows ---
        __shared__ float stab[1024];
        for (int j = threadIdx.x; j < 1024; j += 256)
            stab[j] = sinf((float)j * (6.28318530717958647692f / 1024.0f));
        __syncthreads();
        const int mode = bid >= NB_T;
        ushort_t* T = mode ? T2b : T1b;
        const int i = (bid - mode * NB_T) * 256 + threadIdx.x;
        const int row = i >> 7;
        const int nb  = (i & 127) << 3;
        const int kf  = (row == 1) ? 512 : (row >> 1);
        const bool sb = (row & 1) && (row != 1);        // sine basis?
        float scale = 1.0f;
        if (mode) scale = ((row < 2) ? 1.0f : 2.0f) / 1024.0f;
        ushort_t o[8];
        int m = (kf * nb) & 1023;
#pragma unroll
        for (int j = 0; j < 8; ++j) {
            const float v = sb ? -stab[m] : stab[(m + 256) & 1023];
            o[j] = f2bf(v * scale);
            m = (m + kf) & 1023;
        }
        reinterpret_cast<bf16x8*>(T)[i] = *reinterpret_cast<bf16x8*>(o);
    } else if (bid < 2 * NB_T + NB_TR) {
        // --- Bw transpose-convert ---
        __shared__ float tile[64][65];
        const int b2 = bid - 2 * NB_T;
        const int bx = (b2 & 15) * 64;
        const int by = (b2 >> 4) * 64;
        const int lx = threadIdx.x & 63;
        const int ly = threadIdx.x >> 6;
#pragma unroll
        for (int i = 0; i < 16; ++i) {
            const int r = ly + i * 4;
            tile[r][lx] = Bw[(size_t)(by + r) * DMODEL + bx + lx];
        }
        __syncthreads();
#pragma unroll
        for (int i = 0; i < 16; ++i) {
            const int r = ly + i * 4;
            BwTb[(size_t)(bx + r) * DMODEL + by + lx] = f2bf(tile[lx][r]);
        }
    } else {
        // --- fp32 -> bf16 conversions (u, then Cw) ---
        const int b3 = bid - (2 * NB_T + NB_TR);
        const float* s; ushort_t* d; int i;
        if (b3 < NB_U) { s = u;  d = ub;  i = b3 * 256 + threadIdx.x; }
        else           { s = Cw; d = Cwb; i = (b3 - NB_U) * 256 + threadIdx.x; }
        const float4 a = reinterpret_cast<const float4*>(s)[2 * i];
        const float4 b = reinterpret_cast<const float4*>(s)[2 * i + 1];
        ushort_t o[8] = {f2bf(a.x), f2bf(a.y), f2bf(a.z), f2bf(a.w),
                         f2bf(b.x), f2bf(b.y), f2bf(b.z), f2bf(b.w)};
        reinterpret_cast<bf16x8*>(d)[i] = *reinterpret_cast<bf16x8*>(o);
    }
}

// ---------------------------------------------------------------------------
// 128x128 BK=32 bf16 MFMA GEMM — both weight-precompute GEMMs (blockIdx.z).
// ---------------------------------------------------------------------------
__global__ __launch_bounds__(256) void gemm128z(const ushort_t* __restrict__ A0,
                                                const ushort_t* __restrict__ B0,
                                                ushort_t* __restrict__ C0,
                                                const ushort_t* __restrict__ A1,
                                                const ushort_t* __restrict__ B1,
                                                ushort_t* __restrict__ C1) {
    const int K = 1024, N = 1024;
    const ushort_t* A = blockIdx.z ? A1 : A0;
    const ushort_t* B = blockIdx.z ? B1 : B0;
    ushort_t*       C = blockIdx.z ? C1 : C0;
    __shared__ ushort_t As[128 * 32];
    __shared__ ushort_t Bs[128 * 32];
    const int tid  = threadIdx.x;
    const int lane = tid & 63;
    const int w    = tid >> 6;
    const int m0 = blockIdx.x * 128;
    const int n0 = blockIdx.y * 128;
    const int wr = (w >> 1) * 64;
    const int wc = (w & 1) * 64;

    f32x4 acc[4][4] = {};

    const int pos  = w * 512 + lane * 8;
    const int srow = pos >> 5;
    const int scol = pos & 31;
    const int lr = lane & 15;
    const int lk = (lane >> 4) * 8;

    for (int k0 = 0; k0 < K; k0 += 32) {
        __syncthreads();
        async_cp16(A + (size_t)(m0 + srow)      * K + k0 + scol, As + w * 512);
        async_cp16(A + (size_t)(m0 + srow + 64) * K + k0 + scol, As + 2048 + w * 512);
        async_cp16(B + (size_t)(n0 + srow)      * K + k0 + scol, Bs + w * 512);
        async_cp16(B + (size_t)(n0 + srow + 64) * K + k0 + scol, Bs + 2048 + w * 512);
        __syncthreads();

        bf16x8 fa[4], fb[4];
#pragma unroll
        for (int mi = 0; mi < 4; ++mi)
            fa[mi] = *reinterpret_cast<const bf16x8*>(&As[(wr + mi * 16 + lr) * 32 + lk]);
#pragma unroll
        for (int ni = 0; ni < 4; ++ni)
            fb[ni] = *reinterpret_cast<const bf16x8*>(&Bs[(wc + ni * 16 + lr) * 32 + lk]);
#pragma unroll
        for (int mi = 0; mi < 4; ++mi)
#pragma unroll
            for (int ni = 0; ni < 4; ++ni)
                acc[mi][ni] = __builtin_amdgcn_mfma_f32_16x16x32_bf16(
                    fa[mi], fb[ni], acc[mi][ni], 0, 0, 0);
    }

    const int rbase = (lane >> 4) * 4;
#pragma unroll
    for (int mi = 0; mi < 4; ++mi)
#pragma unroll
        for (int ni = 0; ni < 4; ++ni) {
            const int col = n0 + wc + ni * 16 + lr;
#pragma unroll
            for (int j = 0; j < 4; ++j) {
                const int row = m0 + wr + mi * 16 + rbase + j;
                C[(size_t)row * N + col] = f2bf(acc[mi][ni][j]);
            }
        }
}

// ---------------------------------------------------------------------------
// Generalized pair recurrence coefficients (j=0 packs DC + Nyquist reals).
// ---------------------------------------------------------------------------
__device__ __forceinline__ void pair_coef(const float* lam, int j,
                                          float& lr, float& lr2, float& cr) {
    const float a = lam[2 * j];
    const float b = lam[2 * j + 1];
    if (j == 0) { lr = a; lr2 = b; cr = 0.0f; }
    else        { lr = a; lr2 = a; cr = b; }
}

// ---------------------------------------------------------------------------
// 256x256 8-wave bf16 MFMA GEMM — m201-style 8-phase schedule (round-8 proven,
// staging/loop byte-identical; epilogue switched by SCANEPI).
// SCANEPI=1: dump acc -> LDS, per-thread 64-step local scans, write H_local
//            (bf16 pairs) to Cv and chunk-end states to G.
// SCANEPI=0: fp32 C write with optional D*u epilogue (dflag).
// ---------------------------------------------------------------------------
template <int MH, int NH>
__device__ __forceinline__ void quad_mfma(f32x4 (&acc)[2][2][4][2],
                                          const bf16x8 (&fa)[4][2],
                                          const bf16x8 (&fb)[2][2]) {
#pragma unroll
    for (int mi = 0; mi < 4; ++mi)
#pragma unroll
        for (int ni = 0; ni < 2; ++ni) {
            acc[MH][NH][mi][ni] = __builtin_amdgcn_mfma_f32_16x16x32_bf16(
                fa[mi][0], fb[ni][0], acc[MH][NH][mi][ni], 0, 0, 0);
            acc[MH][NH][mi][ni] = __builtin_amdgcn_mfma_f32_16x16x32_bf16(
                fa[mi][1], fb[ni][1], acc[MH][NH][mi][ni], 0, 0, 0);
        }
}

__device__ __forceinline__ void ld_fa(bf16x8 (&fa)[4][2], const ushort_t* hb,
                                      int wm, int lr, int c0, int c1) {
#pragma unroll
    for (int mi = 0; mi < 4; ++mi) {
        const ushort_t* p = hb + (wm * 64 + mi * 16 + lr) * 64;
        fa[mi][0] = *reinterpret_cast<const bf16x8*>(p + c0);
        fa[mi][1] = *reinterpret_cast<const bf16x8*>(p + c1);
    }
}
__device__ __forceinline__ void ld_fb(bf16x8 (&fb)[2][2], const ushort_t* hb,
                                      int wn, int lr, int c0, int c1) {
#pragma unroll
    for (int ni = 0; ni < 2; ++ni) {
        const ushort_t* p = hb + (wn * 32 + ni * 16 + lr) * 64;
        fb[ni][0] = *reinterpret_cast<const bf16x8*>(p + c0);
        fb[ni][1] = *reinterpret_cast<const bf16x8*>(p + c1);
    }
}

#define HS_STRIDE 260    // ushort stride: dump-writes and scan-reads both <=2 lanes/bank

template <bool SCANEPI>
__global__ __launch_bounds__(512, 2) void gemm256(const ushort_t* __restrict__ A,
                                                  const ushort_t* __restrict__ B,
                                                  void* __restrict__ Cv,
                                                  int M, int K,
                                                  const float* __restrict__ uu,
                                                  const float* __restrict__ Dv,
                                                  const int* __restrict__ dflag,
                                                  const float* __restrict__ lam,
                                                  float2* __restrict__ G) {
    __shared__ ushort_t smem[66560];   // As/Bs (65536) aliased with Hs (66560) = 133120 B
    const int tid  = threadIdx.x;
    const int lane = tid & 63;
    const int w    = tid >> 6;      // 0..7
    const int wm   = w >> 2;        // 0..1
    const int wn   = w & 3;         // 0..3
    const int m0 = blockIdx.x * 256;
    const int n0 = blockIdx.y * 256;
    const int lr = lane & 15;
    const int lk = (lane >> 4) * 8;
    const int xv = (lr & 7) << 3;
    const int c0 = lk ^ xv;
    const int c1 = (32 + lk) ^ xv;

    const int rA = tid >> 3;                             // staging row 0..63
    const int cS = ((tid & 7) << 3) ^ ((rA & 7) << 3);   // pre-swizzled src col
    const int ldsOff = w << 9;

    // As[buf][half] = smem + (buf*2+half)*8192 ; Bs at +32768
    auto ApH = [&](int buf, int half) { return smem + (buf * 2 + half) * 8192; };
    auto BpH = [&](int buf, int half) { return smem + 32768 + (buf * 2 + half) * 8192; };

    f32x4 acc[2][2][4][2] = {};
    bf16x8 fa[4][2], fbl[2][2], fbh[2][2];

    auto stA = [&](int buf, int half, int k) {
#pragma unroll
        for (int li = 0; li < 2; ++li)
            async_cp16(A + (size_t)(m0 + half * 128 + li * 64 + rA) * K + k + cS,
                       ApH(buf, half) + li * 4096 + ldsOff);
    };
    auto stB = [&](int buf, int half, int k) {
#pragma unroll
        for (int li = 0; li < 2; ++li)
            async_cp16(B + (size_t)(n0 + half * 128 + li * 64 + rA) * K + k + cS,
                       BpH(buf, half) + li * 4096 + ldsOff);
    };

    // prologue: tile0 fully, tile1 minus A-hi
    stA(0, 0, 0); stB(0, 0, 0); stB(0, 1, 0); stA(0, 1, 0);
    stA(1, 0, 64); stB(1, 0, 64); stB(1, 1, 64);
    VM6();
    BAR();

    const int niter = K >> 7;
#pragma unroll 1
    for (int t = 0; t < niter - 1; ++t) {
        const int kb1 = (t << 7) + 64;
        const int kn  = (t + 1) << 7;
        const int kn2 = kn + 64;
        // P1
        ld_fa(fa, ApH(0, 0), wm, lr, c0, c1);
        ld_fb(fbl, BpH(0, 0), wn, lr, c0, c1);
        stA(1, 1, kb1);
        LGKM8();
        BAR(); LGKM0();
        PRIO1(); quad_mfma<0, 0>(acc, fa, fbl); PRIO0();
        BAR();
        // P2
        ld_fb(fbh, BpH(0, 1), wn, lr, c0, c1);
        stA(0, 0, kn);
        BAR(); LGKM0();
        PRIO1(); quad_mfma<0, 1>(acc, fa, fbh); PRIO0();
        BAR();
        // P3
        ld_fa(fa, ApH(0, 1), wm, lr, c0, c1);
        stB(0, 0, kn);
        BAR(); LGKM0();
        PRIO1(); quad_mfma<1, 1>(acc, fa, fbh); PRIO0();
        BAR();
        // P4
        stB(0, 1, kn);
        VM6();
        BAR();
        PRIO1(); quad_mfma<1, 0>(acc, fa, fbl); PRIO0();
        BAR();
        // P5
        ld_fa(fa, ApH(1, 0), wm, lr, c0, c1);
        ld_fb(fbl, BpH(1, 0), wn, lr, c0, c1);
        stA(0, 1, kn);
        LGKM8();
        BAR(); LGKM0();
        PRIO1(); quad_mfma<0, 0>(acc, fa, fbl); PRIO0();
        BAR();
        // P6
        ld_fb(fbh, BpH(1, 1), wn, lr, c0, c1);
        stA(1, 0, kn2);
        BAR(); LGKM0();
        PRIO1(); quad_mfma<0, 1>(acc, fa, fbh); PRIO0();
        BAR();
        // P7
        ld_fa(fa, ApH(1, 1), wm, lr, c0, c1);
        stB(1, 0, kn2);
        BAR(); LGKM0();
        PRIO1(); quad_mfma<1, 1>(acc, fa, fbh); PRIO0();
        BAR();
        // P8
        stB(1, 1, kn2);
        VM6();
        BAR();
        PRIO1(); quad_mfma<1, 0>(acc, fa, fbl); PRIO0();
        BAR();
    }
    // epilogue iteration
    {
        const int kb1 = ((niter - 1) << 7) + 64;
        ld_fa(fa, ApH(0, 0), wm, lr, c0, c1);
        ld_fb(fbl, BpH(0, 0), wn, lr, c0, c1);
        stA(1, 1, kb1);
        LGKM8();
        BAR(); LGKM0();
        PRIO1(); quad_mfma<0, 0>(acc, fa, fbl); PRIO0();
        BAR();
        ld_fb(fbh, BpH(0, 1), wn, lr, c0, c1);
        BAR(); LGKM0();
        PRIO1(); quad_mfma<0, 1>(acc, fa, fbh); PRIO0();
        BAR();
        ld_fa(fa, ApH(0, 1), wm, lr, c0, c1);
        BAR(); LGKM0();
        PRIO1(); quad_mfma<1, 1>(acc, fa, fbh); PRIO0();
        BAR();
        VM0();
        BAR();
        PRIO1(); quad_mfma<1, 0>(acc, fa, fbl); PRIO0();
        BAR();
        ld_fa(fa, ApH(1, 0), wm, lr, c0, c1);
        ld_fb(fbl, BpH(1, 0), wn, lr, c0, c1);
        BAR(); LGKM0();
        PRIO1(); quad_mfma<0, 0>(acc, fa, fbl); PRIO0();
        BAR();
        ld_fb(fbh, BpH(1, 1), wn, lr, c0, c1);
        BAR(); LGKM0();
        PRIO1(); quad_mfma<0, 1>(acc, fa, fbh); PRIO0();
        BAR();
        ld_fa(fa, ApH(1, 1), wm, lr, c0, c1);
        BAR(); LGKM0();
        PRIO1(); quad_mfma<1, 1>(acc, fa, fbh); PRIO0();
        BAR();
        PRIO1(); quad_mfma<1, 0>(acc, fa, fbl); PRIO0();
    }

    const int rbase = (lane >> 4) * 4;
    if (SCANEPI) {
        // ---- fused local scan: acc -> LDS -> per-(pair,chunk) recurrence ----
        BAR();   // all waves done with As/Bs reads before aliasing as Hs
#pragma unroll
        for (int mh = 0; mh < 2; ++mh)
#pragma unroll
            for (int nh = 0; nh < 2; ++nh)
#pragma unroll
                for (int mi = 0; mi < 4; ++mi)
#pragma unroll
                    for (int ni = 0; ni < 2; ++ni) {
                        const int cl = nh * 128 + wn * 32 + ni * 16 + lr;
#pragma unroll
                        for (int j = 0; j < 4; ++j) {
                            const int rl = mh * 128 + wm * 64 + mi * 16 + rbase + j;
                            smem[rl * HS_STRIDE + cl] = f2bf(acc[mh][nh][mi][ni][j]);
                        }
                    }
        BAR();
        const int chunk = tid >> 7;          // 0..3
        const int p = tid & 127;             // pair within block
        const int jg = (n0 >> 1) + p;        // global pair
        float lr_, lr2_, cr_;
        pair_coef(lam, jg, lr_, lr2_, cr_);
        uint_t* gout = reinterpret_cast<uint_t*>((ushort_t*)Cv +
                        (size_t)(m0 + chunk * TC) * NSPEC) + jg;
        float er = 0.0f, ei = 0.0f;
        for (int t = 0; t < TC; ++t) {
            const uint_t v = *reinterpret_cast<const uint_t*>(
                &smem[(chunk * TC + t) * HS_STRIDE + 2 * p]);
            const float ur = bf2f((ushort_t)(v & 0xFFFF));
            const float ui = bf2f((ushort_t)(v >> 16));
            const float nr = fmaf(lr_, er, fmaf(-cr_, ei, ur));
            const float ni = fmaf(lr2_, ei, fmaf(cr_, er, ui));
            gout[(size_t)t * NPAIR] = (uint_t)f2bf(nr) | ((uint_t)f2bf(ni) << 16);
            er = nr; ei = ni;
        }
        const int b = m0 >> 11;
        const int cg = ((m0 & 2047) >> 6) + chunk;
        G[(size_t)(b * NC + cg) * NPAIR + jg] = make_float2(er, ei);
    } else {
        // ---- fp32 C write with optional D*u ----
        float* C = (float*)Cv;
        const bool du = (*dflag != 0);
#pragma unroll
        for (int mh = 0; mh < 2; ++mh)
#pragma unroll
            for (int nh = 0; nh < 2; ++nh)
#pragma unroll
                for (int mi = 0; mi < 4; ++mi)
#pragma unroll
                    for (int ni = 0; ni < 2; ++ni) {
                        const int col = n0 + nh * 128 + wn * 32 + ni * 16 + lr;
#pragma unroll
                        for (int j = 0; j < 4; ++j) {
                            const int row = m0 + mh * 128 + wm * 64 + mi * 16 + rbase + j;
                            float v = acc[mh][nh][mi][ni][j];
                            if (du) v = fmaf(Dv[col], uu[(size_t)row * DMODEL + col], v);
                            C[(size_t)row * DMODEL + col] = v;
                        }
                    }
    }
}

// ---------------------------------------------------------------------------
// carry over chunks: E_c = state entering chunk c, via Λ^64 (closed-form sq.)
// ---------------------------------------------------------------------------
__global__ __launch_bounds__(256) void scan_carry(const float2* __restrict__ G,
                                                  const float* __restrict__ lam,
                                                  float2* __restrict__ Ac) {
    const int gid = blockIdx.x * 256 + threadIdx.x;   // BATCH*NPAIR
    if (gid >= BATCH * NPAIR) return;
    const int j = gid & (NPAIR - 1);
    const int b = gid >> 9;
    float lr, lr2, cr;
    pair_coef(lam, j, lr, lr2, cr);
    float pr = lr, pr2 = lr2, pc = cr;
    for (int s = 0; s < 6; ++s) {
        const float nr  = pr * pr - pc * pc;
        const float nr2 = pr2 * pr2 - pc * pc;
        const float npc = pc * (pr + pr2);
        pr = nr; pr2 = nr2; pc = npc;
    }
    float er = 0.0f, ei = 0.0f;
    for (int c = 0; c < NC; ++c) {
        const int idx = (b * NC + c) * NPAIR + j;
        Ac[idx] = make_float2(er, ei);
        const float2 g = G[idx];
        const float nr = fmaf(pr, er, fmaf(-pc, ei, g.x));
        const float ni = fmaf(pr2, ei, fmaf(pc, er, g.y));
        er = nr; ei = ni;
    }
}

// ---------------------------------------------------------------------------
// carry broadcast: H[t] = H_local[t] + Λ^{t+1}·E  (in place, bf16 pairs)
// ---------------------------------------------------------------------------
__global__ __launch_bounds__(256) void scan_applyc(ushort_t* __restrict__ UHb,
                                                   const float* __restrict__ lam,
                                                   const float2* __restrict__ Ac) {
    const int gid = blockIdx.x * 256 + threadIdx.x;   // BATCH*NC*NPAIR
    const int j = gid & (NPAIR - 1);
    const int c = (gid >> 9) & (NC - 1);
    const int b = gid >> 14;
    if (c == 0) return;                        // carry is zero
    float lr, lr2, cr;
    pair_coef(lam, j, lr, lr2, cr);
    const float2 e = Ac[(b * NC + c) * NPAIR + j];
    // s = Λ^{t+1}·e, maintained iteratively starting at Λ·e
    float sr = fmaf(lr, e.x, -cr * e.y);
    float si = fmaf(lr2, e.y, cr * e.x);
    uint_t* base = reinterpret_cast<uint_t*>(
        UHb + (size_t)(b * SEQLEN + c * TC) * NSPEC) + j;
    for (int t = 0; t < TC; ++t) {
        const uint_t v = base[(size_t)t * NPAIR];
        const float hr = bf2f((ushort_t)(v & 0xFFFF)) + sr;
        const float hi = bf2f((ushort_t)(v >> 16)) + si;
        base[(size_t)t * NPAIR] = (uint_t)f2bf(hr) | ((uint_t)f2bf(hi) << 16);
        const float nsr = fmaf(lr, sr, -cr * si);
        const float nsi = fmaf(lr2, si, cr * sr);
        sr = nsr; si = nsi;
    }
}

// ---------------------------------------------------------------------------
extern "C" void kernel_launch(void* const* d_in, const int* in_sizes, int n_in,
                              void* d_out, int out_size, void* d_ws, size_t ws_size,
                              hipStream_t stream) {
    const float* u  = (const float*)d_in[0];  // [B][S][D]
    const float* ap = (const float*)d_in[1];  // [512]
    const float* Bw = (const float*)d_in[2];  // [N][D]
    const float* Cw = (const float*)d_in[3];  // [D][N]
    const float* Dv = (const float*)d_in[4];  // [D]
    float* out = (float*)d_out;               // [B][S][D]

    char* ws = (char*)d_ws;
    size_t off = 0;
    auto carve = [&](size_t bytes) { char* p = ws + off; off += (bytes + 255) & ~(size_t)255; return p; };

    ushort_t* UHb  = (ushort_t*)carve((size_t)BT_ROWS * NSPEC * sizeof(ushort_t));  // 33.6 MB
    ushort_t* ub   = (ushort_t*)carve((size_t)BT_ROWS * DMODEL * sizeof(ushort_t)); // 33.6 MB
    ushort_t* T1b  = (ushort_t*)carve((size_t)NSPEC * DMODEL * sizeof(ushort_t));
    ushort_t* T2b  = (ushort_t*)carve((size_t)NSPEC * DMODEL * sizeof(ushort_t));
    ushort_t* BwTb = (ushort_t*)carve((size_t)DMODEL * DMODEL * sizeof(ushort_t));
    ushort_t* Cwb  = (ushort_t*)carve((size_t)DMODEL * DMODEL * sizeof(ushort_t));
    ushort_t* W1b  = (ushort_t*)carve((size_t)NSPEC * DMODEL * sizeof(ushort_t));
    ushort_t* W2b  = (ushort_t*)carve((size_t)DMODEL * NSPEC * sizeof(ushort_t));
    float*    lam  = (float*)   carve(NSPEC * sizeof(float));
    int*      dflag= (int*)     carve(sizeof(int));
    float2*   G    = (float2*)  carve((size_t)BATCH * NC * NPAIR * sizeof(float2));
    float2*   Ac   = (float2*)  carve((size_t)BATCH * NC * NPAIR * sizeof(float2));

    // 1) eigenvalues + D flag
    compute_lambda<<<1, 1024, 0, stream>>>(ap, lam, Dv, dflag);

    // 2) all prep in one dispatch
    prep_all<<<2 * NB_T + NB_TR + NB_U + NB_CW, 256, 0, stream>>>(
        u, ub, Cw, Cwb, Bw, BwTb, T1b, T2b);

    // 3) both precompute GEMMs in one dispatch
    {
        dim3 g(8, 8, 2);
        gemm128z<<<g, 256, 0, stream>>>(T1b, BwTb, W1b, Cwb, T2b, W2b);
    }

    // 4) GEMM-U + fused local scan (writes H_local to UHb, chunk ends to G)
    {
        dim3 g(BT_ROWS / 256, NSPEC / 256);
        gemm256<true><<<g, 512, 0, stream>>>(ub, W1b, UHb,
            BT_ROWS, DMODEL, nullptr, nullptr, dflag, lam, G);
    }

    // 5) carries + broadcast
    scan_carry<<<(BATCH * NPAIR + 255) / 256, 256, 0, stream>>>(G, lam, Ac);
    scan_applyc<<<BATCH * NC * NPAIR / 256, 256, 0, stream>>>(UHb, lam, Ac);

    // 6) y = UHb @ W2b^T + D*u
    {
        dim3 g(BT_ROWS / 256, DMODEL / 256);
        gemm256<false><<<g, 512, 0, stream>>>(UHb, W2b, out,
            BT_ROWS, NSPEC, u, Dv, dflag, lam, nullptr);
    }
}